// Round 1
// baseline (1241.752 us; speedup 1.0000x reference)
//
#include <hip/hip_runtime.h>
#include <hip/hip_bf16.h>
#include <math.h>

typedef __attribute__((ext_vector_type(8))) __bf16 bf16x8;
typedef __attribute__((ext_vector_type(4))) float f32x4;

#define LL 1024
#define DD 1024
#define HH 16

// ---------------- weight transpose + fp32->bf16 ----------------
// W: R x C fp32  ->  Wt: C x R bf16
__global__ __launch_bounds__(256) void transpose_cvt(const float* __restrict__ W,
                                                     __hip_bfloat16* __restrict__ Wt,
                                                     int R, int C) {
  __shared__ float tile[32][33];
  int tx = threadIdx.x;
  int r0 = blockIdx.y * 32, c0 = blockIdx.x * 32;
  int r = tx >> 3, c4 = (tx & 7) * 4;
  float4 v = *(const float4*)&W[(size_t)(r0 + r) * C + c0 + c4];
  tile[r][c4 + 0] = v.x; tile[r][c4 + 1] = v.y;
  tile[r][c4 + 2] = v.z; tile[r][c4 + 3] = v.w;
  __syncthreads();
  int c = tx >> 3, r4 = (tx & 7) * 4;
  __hip_bfloat16 o[4];
#pragma unroll
  for (int j = 0; j < 4; ++j) o[j] = __float2bfloat16(tile[r4 + j][c]);
  *(uint2*)&Wt[(size_t)(c0 + c) * R + r0 + r4] = *(const uint2*)o;
}

// ---------------- layernorm (fp32 in -> bf16 out) ----------------
__global__ __launch_bounds__(256) void ln_kernel(const float* __restrict__ X,
                                                 const float* __restrict__ w,
                                                 const float* __restrict__ b,
                                                 __hip_bfloat16* __restrict__ out) {
  int row = blockIdx.x;
  int tid = threadIdx.x;
  const float* xr = X + (size_t)row * DD;
  float4 v = *(const float4*)&xr[tid * 4];
  float s = v.x + v.y + v.z + v.w;
  float s2 = v.x * v.x + v.y * v.y + v.z * v.z + v.w * v.w;
#pragma unroll
  for (int m = 1; m < 64; m <<= 1) {
    s += __shfl_xor(s, m);
    s2 += __shfl_xor(s2, m);
  }
  __shared__ float ps[4], ps2[4];
  int wv_ = tid >> 6, lane = tid & 63;
  if (lane == 0) { ps[wv_] = s; ps2[wv_] = s2; }
  __syncthreads();
  float ts = ps[0] + ps[1] + ps[2] + ps[3];
  float ts2 = ps2[0] + ps2[1] + ps2[2] + ps2[3];
  float mu = ts * (1.0f / DD);
  float var = ts2 * (1.0f / DD) - mu * mu;
  float rs = rsqrtf(var + 1e-5f);
  float4 wv = *(const float4*)&w[tid * 4];
  float4 bv = *(const float4*)&b[tid * 4];
  __hip_bfloat16 o[4];
  o[0] = __float2bfloat16((v.x - mu) * rs * wv.x + bv.x);
  o[1] = __float2bfloat16((v.y - mu) * rs * wv.y + bv.y);
  o[2] = __float2bfloat16((v.z - mu) * rs * wv.z + bv.z);
  o[3] = __float2bfloat16((v.w - mu) * rs * wv.w + bv.w);
  *(uint2*)&out[(size_t)row * DD + tid * 4] = *(const uint2*)o;
}

// ---------------- bf16 MFMA GEMM:  C = A(MxK) * Bt(NxK)^T + bias ----------------
// EPI: 0 = bf16 out, 1 = exact GELU -> bf16 out, 2 = fp32 out with residual add
template <int EPI>
__global__ __launch_bounds__(256) void gemm_bf16(const __hip_bfloat16* __restrict__ A,
                                                 const __hip_bfloat16* __restrict__ Bt,
                                                 const float* __restrict__ bias,
                                                 const float* __restrict__ resid,
                                                 void* __restrict__ Cout,
                                                 int M, int N, int K) {
  __shared__ __hip_bfloat16 a_lds[64][40];  // 32 + 8 pad (rows 80B, 16B-aligned)
  __shared__ __hip_bfloat16 b_lds[64][40];
  int tid = threadIdx.x;
  int lane = tid & 63, w = tid >> 6;
  int bm0 = blockIdx.y * 64, bn0 = blockIdx.x * 64;
  int srow = tid >> 2, sk0 = (tid & 3) * 8;
  f32x4 acc[4] = {};
  const int fr = lane & 15, fk = (lane >> 4) * 8;

  for (int kk = 0; kk < K; kk += 32) {
    uint4 av = *(const uint4*)&A[(size_t)(bm0 + srow) * K + kk + sk0];
    uint4 bv = *(const uint4*)&Bt[(size_t)(bn0 + srow) * K + kk + sk0];
    __syncthreads();
    *(uint4*)&a_lds[srow][sk0] = av;
    *(uint4*)&b_lds[srow][sk0] = bv;
    __syncthreads();
    bf16x8 af = *(const bf16x8*)&a_lds[16 * w + fr][fk];
#pragma unroll
    for (int f = 0; f < 4; ++f) {
      bf16x8 bfr = *(const bf16x8*)&b_lds[16 * f + fr][fk];
      acc[f] = __builtin_amdgcn_mfma_f32_16x16x32_bf16(af, bfr, acc[f], 0, 0, 0);
    }
  }

  int row0 = bm0 + 16 * w + (lane >> 4) * 4;
#pragma unroll
  for (int f = 0; f < 4; ++f) {
    int col = bn0 + 16 * f + fr;
    float bsv = bias[col];
#pragma unroll
    for (int j = 0; j < 4; ++j) {
      int row = row0 + j;
      float v = acc[f][j] + bsv;
      if (EPI == 1) v = 0.5f * v * (1.0f + erff(v * 0.7071067811865476f));
      if (EPI == 2) {
        ((float*)Cout)[(size_t)row * N + col] = v + resid[(size_t)row * N + col];
      } else {
        ((__hip_bfloat16*)Cout)[(size_t)row * N + col] = __float2bfloat16(v);
      }
    }
  }
}

// ---------------- fused causal attention with relative-position skew ----------------
// Srel[l,c] = q[l] . Er[LL-1 + c - l]   (valid for c <= l; masked otherwise)
union BU { uint4 u; __hip_bfloat16 h[8]; };

__global__ __launch_bounds__(256) void attn_fused(const __hip_bfloat16* __restrict__ qkv,
                                                  const float* __restrict__ Er,
                                                  __hip_bfloat16* __restrict__ Y) {
  __shared__ float q_lds[4][64];
  __shared__ float k_lds[64][72];   // stride 288B: 16B-aligned float4 rows
  __shared__ float vT_lds[64][65];  // transposed V, scalar reads conflict-free
  __shared__ float er_lds[68][72];
  __shared__ float p_lds[4][64];

  int bid = blockIdx.x;
  int rb = bid & 255;        // L/4 = 256 row-blocks
  int bh = bid >> 8;
  int h = bh & 15, b = bh >> 4;
  int l0 = rb * 4;
  int tid = threadIdx.x, lane = tid & 63, w = tid >> 6;
  int l = l0 + w;

  const __hip_bfloat16* qbase = qkv + (size_t)b * LL * 3072 + h * 64;

  {  // stage q rows (one per wave)
    int r = tid >> 6, d = tid & 63;
    q_lds[r][d] = __bfloat162float(qbase[(size_t)(l0 + r) * 3072 + d]);
  }

  float m_run = -1e30f, s_run = 0.f, yacc = 0.f;
  int ntiles = (l0 + 3) / 64 + 1;

  for (int t = 0; t < ntiles; ++t) {
    int c0 = t * 64;
    __syncthreads();  // protect LDS reuse (also covers q staging on t==0)
    {  // stage k, v tiles (bf16 -> fp32)
      int r = tid >> 2, d0 = (tid & 3) * 16;
      const __hip_bfloat16* krow = qbase + 1024 + (size_t)(c0 + r) * 3072 + d0;
      const __hip_bfloat16* vrow = qbase + 2048 + (size_t)(c0 + r) * 3072 + d0;
      BU k0, k1, v0, v1;
      k0.u = *(const uint4*)krow; k1.u = *(const uint4*)(krow + 8);
      v0.u = *(const uint4*)vrow; v1.u = *(const uint4*)(vrow + 8);
#pragma unroll
      for (int j = 0; j < 8; ++j) {
        k_lds[r][d0 + j] = __bfloat162float(k0.h[j]);
        k_lds[r][d0 + 8 + j] = __bfloat162float(k1.h[j]);
        vT_lds[d0 + j][r] = __bfloat162float(v0.h[j]);
        vT_lds[d0 + 8 + j][r] = __bfloat162float(v1.h[j]);
      }
    }
    {  // stage Er band: rows mlo..mlo+66 ; er_lds[i] = Er[clamp(mlo+i)]
      int mlo = 1020 + c0 - l0;
      int d0 = (tid & 3) * 16;
      for (int i = tid >> 2; i < 67; i += 64) {
        int m = min(max(mlo + i, 0), 1023);
        const float* er = Er + (size_t)m * 64 + d0;
        *(float4*)&er_lds[i][d0]      = *(const float4*)er;
        *(float4*)&er_lds[i][d0 + 4]  = *(const float4*)(er + 4);
        *(float4*)&er_lds[i][d0 + 8]  = *(const float4*)(er + 8);
        *(float4*)&er_lds[i][d0 + 12] = *(const float4*)(er + 12);
      }
    }
    __syncthreads();

    if (c0 <= l) {
      float s = 0.f, e = 0.f;
      int ier = 3 + lane - w;  // = (1023 + c - l) - mlo
#pragma unroll
      for (int d4 = 0; d4 < 16; ++d4) {
        float4 qv = *(const float4*)&q_lds[w][d4 * 4];
        float4 kv = *(const float4*)&k_lds[lane][d4 * 4];
        float4 ev = *(const float4*)&er_lds[ier][d4 * 4];
        s += qv.x * kv.x + qv.y * kv.y + qv.z * kv.z + qv.w * kv.w;
        e += qv.x * ev.x + qv.y * ev.y + qv.z * ev.z + qv.w * ev.w;
      }
      int c = c0 + lane;
      float score = (s + e) * 0.125f;
      if (c > l) score = -1e30f;
      float tmax = score;
#pragma unroll
      for (int m_ = 32; m_ >= 1; m_ >>= 1) tmax = fmaxf(tmax, __shfl_xor(tmax, m_));
      float newm = fmaxf(m_run, tmax);
      float p = __expf(score - newm);
      float alpha = __expf(m_run - newm);
      float psum = p;
#pragma unroll
      for (int m_ = 32; m_ >= 1; m_ >>= 1) psum += __shfl_xor(psum, m_);
      s_run = s_run * alpha + psum;
      yacc *= alpha;
      m_run = newm;
      p_lds[w][lane] = p;
      // PV: yacc(d=lane) += sum_c p[c] * v[c][lane]
#pragma unroll
      for (int cj = 0; cj < 16; ++cj) {
        float4 pv = *(const float4*)&p_lds[w][cj * 4];
        yacc += pv.x * vT_lds[lane][cj * 4 + 0]
              + pv.y * vT_lds[lane][cj * 4 + 1]
              + pv.z * vT_lds[lane][cj * 4 + 2]
              + pv.w * vT_lds[lane][cj * 4 + 3];
      }
    }
  }
  float o = yacc / s_run;
  Y[(size_t)(b * LL + l) * DD + h * 64 + lane] = __float2bfloat16(o);
}

// ---------------- launch ----------------
extern "C" void kernel_launch(void* const* d_in, const int* in_sizes, int n_in,
                              void* d_out, int out_size, void* d_ws, size_t ws_size,
                              hipStream_t stream) {
  (void)in_sizes; (void)n_in; (void)out_size; (void)ws_size;
  const float* x     = (const float*)d_in[0];
  const float* ln1w  = (const float*)d_in[1];
  const float* ln1b  = (const float*)d_in[2];
  const float* Wqkv  = (const float*)d_in[3];
  const float* bqkv  = (const float*)d_in[4];
  const float* Wproj = (const float*)d_in[5];
  const float* bproj = (const float*)d_in[6];
  const float* Er    = (const float*)d_in[7];
  const float* ln2w  = (const float*)d_in[8];
  const float* ln2b  = (const float*)d_in[9];
  const float* Wfc   = (const float*)d_in[10];
  const float* bfc   = (const float*)d_in[11];
  const float* Wfc2  = (const float*)d_in[12];
  const float* bfc2  = (const float*)d_in[13];
  float* out = (float*)d_out;

  char* ws = (char*)d_ws;
  const size_t MB = 1ull << 20;
  __hip_bfloat16* h1    = (__hip_bfloat16*)(ws + 0);        // 8 MB
  __hip_bfloat16* qkvb  = (__hip_bfloat16*)(ws + 8 * MB);   // 24 MB
  __hip_bfloat16* mbuf  = (__hip_bfloat16*)(ws + 0);        // 32 MB (aliases h1+qkvb, both dead)
  __hip_bfloat16* yb    = (__hip_bfloat16*)(ws + 32 * MB);  // 8 MB
  __hip_bfloat16* h2    = (__hip_bfloat16*)(ws + 32 * MB);  // 8 MB (aliases yb, dead)
  float*          x2    = (float*)(ws + 40 * MB);           // 16 MB
  __hip_bfloat16* Wqkvt = (__hip_bfloat16*)(ws + 56 * MB);  // 6 MB
  __hip_bfloat16* Wprojt= (__hip_bfloat16*)(ws + 63 * MB);  // 2 MB
  __hip_bfloat16* Wfct  = (__hip_bfloat16*)(ws + 66 * MB);  // 8 MB
  __hip_bfloat16* Wfc2t = (__hip_bfloat16*)(ws + 75 * MB);  // 8 MB  (total 83 MB)

  dim3 blk(256);

  transpose_cvt<<<dim3(3072 / 32, 1024 / 32), blk, 0, stream>>>(Wqkv, Wqkvt, 1024, 3072);
  transpose_cvt<<<dim3(1024 / 32, 1024 / 32), blk, 0, stream>>>(Wproj, Wprojt, 1024, 1024);
  transpose_cvt<<<dim3(4096 / 32, 1024 / 32), blk, 0, stream>>>(Wfc, Wfct, 1024, 4096);
  transpose_cvt<<<dim3(1024 / 32, 4096 / 32), blk, 0, stream>>>(Wfc2, Wfc2t, 4096, 1024);

  ln_kernel<<<4096, blk, 0, stream>>>(x, ln1w, ln1b, h1);

  gemm_bf16<0><<<dim3(3072 / 64, 4096 / 64), blk, 0, stream>>>(
      h1, Wqkvt, bqkv, nullptr, qkvb, 4096, 3072, 1024);

  attn_fused<<<dim3(4 * 16 * 256), blk, 0, stream>>>(qkvb, Er, yb);

  gemm_bf16<2><<<dim3(1024 / 64, 4096 / 64), blk, 0, stream>>>(
      yb, Wprojt, bproj, x, x2, 4096, 1024, 1024);

  ln_kernel<<<4096, blk, 0, stream>>>(x2, ln2w, ln2b, h2);

  gemm_bf16<1><<<dim3(4096 / 64, 4096 / 64), blk, 0, stream>>>(
      h2, Wfct, bfc, nullptr, mbuf, 4096, 4096, 1024);

  gemm_bf16<2><<<dim3(1024 / 64, 4096 / 64), blk, 0, stream>>>(
      mbuf, Wfc2t, bfc2, x2, out, 4096, 1024, 4096);
}

// Round 2
// 357.553 us; speedup vs baseline: 3.4729x; 3.4729x over previous
//
#include <hip/hip_runtime.h>
#include <hip/hip_bf16.h>
#include <math.h>

typedef __attribute__((ext_vector_type(8))) __bf16 bf16x8;
typedef __attribute__((ext_vector_type(4))) float f32x4;

#define LL 1024
#define DD 1024
#define HH 16

// ---------------- weight transpose + fp32->bf16 ----------------
__global__ __launch_bounds__(256) void transpose_cvt(const float* __restrict__ W,
                                                     __hip_bfloat16* __restrict__ Wt,
                                                     int R, int C) {
  __shared__ float tile[32][33];
  int tx = threadIdx.x;
  int r0 = blockIdx.y * 32, c0 = blockIdx.x * 32;
  int r = tx >> 3, c4 = (tx & 7) * 4;
  float4 v = *(const float4*)&W[(size_t)(r0 + r) * C + c0 + c4];
  tile[r][c4 + 0] = v.x; tile[r][c4 + 1] = v.y;
  tile[r][c4 + 2] = v.z; tile[r][c4 + 3] = v.w;
  __syncthreads();
  int c = tx >> 3, r4 = (tx & 7) * 4;
  __hip_bfloat16 o[4];
#pragma unroll
  for (int j = 0; j < 4; ++j) o[j] = __float2bfloat16(tile[r4 + j][c]);
  *(uint2*)&Wt[(size_t)(c0 + c) * R + r0 + r4] = *(const uint2*)o;
}

// ---------------- layernorm (fp32 in -> bf16 out) ----------------
__global__ __launch_bounds__(256) void ln_kernel(const float* __restrict__ X,
                                                 const float* __restrict__ w,
                                                 const float* __restrict__ b,
                                                 __hip_bfloat16* __restrict__ out) {
  int row = blockIdx.x;
  int tid = threadIdx.x;
  const float* xr = X + (size_t)row * DD;
  float4 v = *(const float4*)&xr[tid * 4];
  float s = v.x + v.y + v.z + v.w;
  float s2 = v.x * v.x + v.y * v.y + v.z * v.z + v.w * v.w;
#pragma unroll
  for (int m = 1; m < 64; m <<= 1) {
    s += __shfl_xor(s, m);
    s2 += __shfl_xor(s2, m);
  }
  __shared__ float ps[4], ps2[4];
  int wv_ = tid >> 6, lane = tid & 63;
  if (lane == 0) { ps[wv_] = s; ps2[wv_] = s2; }
  __syncthreads();
  float ts = ps[0] + ps[1] + ps[2] + ps[3];
  float ts2 = ps2[0] + ps2[1] + ps2[2] + ps2[3];
  float mu = ts * (1.0f / DD);
  float var = ts2 * (1.0f / DD) - mu * mu;
  float rs = rsqrtf(var + 1e-5f);
  float4 wv = *(const float4*)&w[tid * 4];
  float4 bv = *(const float4*)&b[tid * 4];
  __hip_bfloat16 o[4];
  o[0] = __float2bfloat16((v.x - mu) * rs * wv.x + bv.x);
  o[1] = __float2bfloat16((v.y - mu) * rs * wv.y + bv.y);
  o[2] = __float2bfloat16((v.z - mu) * rs * wv.z + bv.z);
  o[3] = __float2bfloat16((v.w - mu) * rs * wv.w + bv.w);
  *(uint2*)&out[(size_t)row * DD + tid * 4] = *(const uint2*)o;
}

// ---------------- bf16 MFMA GEMM:  C = A(MxK) * Bt(NxK)^T + bias ----------------
template <int EPI>
__global__ __launch_bounds__(256) void gemm_bf16(const __hip_bfloat16* __restrict__ A,
                                                 const __hip_bfloat16* __restrict__ Bt,
                                                 const float* __restrict__ bias,
                                                 const float* __restrict__ resid,
                                                 void* __restrict__ Cout,
                                                 int M, int N, int K) {
  __shared__ __hip_bfloat16 a_lds[64][40];
  __shared__ __hip_bfloat16 b_lds[64][40];
  int tid = threadIdx.x;
  int lane = tid & 63, w = tid >> 6;
  int bm0 = blockIdx.y * 64, bn0 = blockIdx.x * 64;
  int srow = tid >> 2, sk0 = (tid & 3) * 8;
  f32x4 acc[4] = {};
  const int fr = lane & 15, fk = (lane >> 4) * 8;

  for (int kk = 0; kk < K; kk += 32) {
    uint4 av = *(const uint4*)&A[(size_t)(bm0 + srow) * K + kk + sk0];
    uint4 bv = *(const uint4*)&Bt[(size_t)(bn0 + srow) * K + kk + sk0];
    __syncthreads();
    *(uint4*)&a_lds[srow][sk0] = av;
    *(uint4*)&b_lds[srow][sk0] = bv;
    __syncthreads();
    bf16x8 af = *(const bf16x8*)&a_lds[16 * w + fr][fk];
#pragma unroll
    for (int f = 0; f < 4; ++f) {
      bf16x8 bfr = *(const bf16x8*)&b_lds[16 * f + fr][fk];
      acc[f] = __builtin_amdgcn_mfma_f32_16x16x32_bf16(af, bfr, acc[f], 0, 0, 0);
    }
  }

  int row0 = bm0 + 16 * w + (lane >> 4) * 4;
#pragma unroll
  for (int f = 0; f < 4; ++f) {
    int col = bn0 + 16 * f + fr;
    float bsv = bias[col];
#pragma unroll
    for (int j = 0; j < 4; ++j) {
      int row = row0 + j;
      float v = acc[f][j] + bsv;
      if (EPI == 1) v = 0.5f * v * (1.0f + erff(v * 0.7071067811865476f));
      if (EPI == 2) {
        ((float*)Cout)[(size_t)row * N + col] = v + resid[(size_t)row * N + col];
      } else {
        ((__hip_bfloat16*)Cout)[(size_t)row * N + col] = __float2bfloat16(v);
      }
    }
  }
}

// ---------------- MFMA flash attention with relative-position skew ----------------
// Block = one (b,h) and a 64-row Q tile. 4 waves x 16 query rows.
// Srel[l,c] = q[l] . Er[1023 + c - l]; per ktile: Toeplitz band GEMM
// G[li, jj] = q[l0+li] . Er[960 + c0 - l0 + jj], jj in [0,126];
// Srel(tile) = G[li][c - li + 63].
__global__ __launch_bounds__(256) void attn_mfma(const __hip_bfloat16* __restrict__ qkv,
                                                 const float* __restrict__ Er,
                                                 __hip_bfloat16* __restrict__ Y) {
  __shared__ __hip_bfloat16 q_s[64][72];
  __shared__ __hip_bfloat16 k_s[64][72];
  __shared__ __hip_bfloat16 er_s[128][72];
  __shared__ __hip_bfloat16 p_s[4][16][72];
  __shared__ __hip_bfloat16 g_s[4][16][136];
  __shared__ __hip_bfloat16 vt_s[64 * 64];  // transposed V, XOR-swizzled

  int bid = blockIdx.x;
  int qi = 15 - (bid >> 6);     // heavy tiles first
  int head = bid & 63;
  int h = head & 15, b = head >> 4;
  int l0 = qi * 64;
  int tid = threadIdx.x, lane = tid & 63, w = tid >> 6;

  const __hip_bfloat16* base = qkv + (size_t)b * (LL * 3072) + h * 64;

  {  // stage Q (64x64 bf16)
    int r = tid >> 2, d0 = (tid & 3) * 16;
    const __hip_bfloat16* src = base + (size_t)(l0 + r) * 3072 + d0;
    *(uint4*)&q_s[r][d0] = *(const uint4*)src;
    *(uint4*)&q_s[r][d0 + 8] = *(const uint4*)(src + 8);
  }
  __syncthreads();
  bf16x8 qf[2];
  {
    int r = 16 * w + (lane & 15), kc = (lane >> 4) * 8;
    qf[0] = *(const bf16x8*)&q_s[r][kc];
    qf[1] = *(const bf16x8*)&q_s[r][kc + 32];
  }

  f32x4 oacc[4] = {};
  float m_run[4], s_run[4];
#pragma unroll
  for (int j = 0; j < 4; ++j) { m_run[j] = -1e30f; s_run[j] = 0.f; }

  for (int t = 0; t <= qi; ++t) {
    int c0 = t * 64;
    __syncthreads();  // prior iteration done with k_s/vt_s/er_s
    {  // stage K row-major
      int r = tid >> 2, d0 = (tid & 3) * 16;
      const __hip_bfloat16* src = base + 1024 + (size_t)(c0 + r) * 3072 + d0;
      *(uint4*)&k_s[r][d0] = *(const uint4*)src;
      *(uint4*)&k_s[r][d0 + 8] = *(const uint4*)(src + 8);
    }
    {  // stage V transposed + swizzled: vt[d][c], byte = (d<<7)+2c ^ swz(d)<<4
      int c = (tid >> 3) * 2, d0 = (tid & 7) * 8;
      const __hip_bfloat16* s0 = base + 2048 + (size_t)(c0 + c) * 3072 + d0;
      uint4 u0 = *(const uint4*)s0;
      uint4 u1 = *(const uint4*)(s0 + 3072);
      const uint16_t* h0 = (const uint16_t*)&u0;
      const uint16_t* h1 = (const uint16_t*)&u1;
#pragma unroll
      for (int j = 0; j < 8; ++j) {
        int d = d0 + j;
        uint32_t pk = (uint32_t)h0[j] | ((uint32_t)h1[j] << 16);
        uint32_t byte = ((uint32_t)d << 7) + 2u * (uint32_t)c;
        byte ^= (uint32_t)(((d & 7) ^ (d >> 3)) << 4);
        *(uint32_t*)((char*)vt_s + byte) = pk;
      }
    }
    {  // stage Er band rows 0..127 (bf16), clamped
      int jj = tid >> 1, ch = (tid & 1) * 32;
      int m = 960 + c0 - l0 + jj;
      m = min(max(m, 0), 1023);
      const float* src = Er + (size_t)m * 64 + ch;
#pragma unroll
      for (int i = 0; i < 8; ++i) {
        float4 v = *(const float4*)(src + 4 * i);
        __hip_bfloat16 o[4];
        o[0] = __float2bfloat16(v.x); o[1] = __float2bfloat16(v.y);
        o[2] = __float2bfloat16(v.z); o[3] = __float2bfloat16(v.w);
        *(uint2*)&er_s[jj][ch + 4 * i] = *(const uint2*)o;
      }
    }
    __syncthreads();

    // ---- S = Q K^T (wave rows 16w..16w+15, cols 0..63) ----
    f32x4 sacc[4] = {};
#pragma unroll
    for (int f = 0; f < 4; ++f) {
      int cc = 16 * f + (lane & 15), kc = (lane >> 4) * 8;
      bf16x8 k0 = *(const bf16x8*)&k_s[cc][kc];
      bf16x8 k1 = *(const bf16x8*)&k_s[cc][kc + 32];
      sacc[f] = __builtin_amdgcn_mfma_f32_16x16x32_bf16(qf[0], k0, sacc[f], 0, 0, 0);
      sacc[f] = __builtin_amdgcn_mfma_f32_16x16x32_bf16(qf[1], k1, sacc[f], 0, 0, 0);
    }
    // ---- G = Q ErBand^T (cols 0..127), spill to LDS (per-wave region) ----
#pragma unroll
    for (int g = 0; g < 8; ++g) {
      int cc = 16 * g + (lane & 15), kc = (lane >> 4) * 8;
      bf16x8 e0 = *(const bf16x8*)&er_s[cc][kc];
      bf16x8 e1 = *(const bf16x8*)&er_s[cc][kc + 32];
      f32x4 gacc = {};
      gacc = __builtin_amdgcn_mfma_f32_16x16x32_bf16(qf[0], e0, gacc, 0, 0, 0);
      gacc = __builtin_amdgcn_mfma_f32_16x16x32_bf16(qf[1], e1, gacc, 0, 0, 0);
#pragma unroll
      for (int j = 0; j < 4; ++j) {
        int r = (lane >> 4) * 4 + j;
        g_s[w][r][16 * g + (lane & 15)] = __float2bfloat16(gacc[j]);
      }
    }

    // ---- softmax (online), rows owned per-lane-group ----
    float sv[4][4];
#pragma unroll
    for (int f = 0; f < 4; ++f) {
#pragma unroll
      for (int j = 0; j < 4; ++j) {
        int r = (lane >> 4) * 4 + j;          // wave-local row 0..15
        int c = 16 * f + (lane & 15);         // tile col 0..63
        int jj = c - (16 * w + r) + 63;       // band index 0..126
        float g = __bfloat162float(g_s[w][r][jj]);
        float val = (sacc[f][j] + g) * 0.125f;
        if (t == qi && c > 16 * w + r) val = -1e30f;
        sv[f][j] = val;
      }
    }
    float alpha[4];
#pragma unroll
    for (int j = 0; j < 4; ++j) {
      float tm = fmaxf(fmaxf(sv[0][j], sv[1][j]), fmaxf(sv[2][j], sv[3][j]));
      tm = fmaxf(tm, __shfl_xor(tm, 1));
      tm = fmaxf(tm, __shfl_xor(tm, 2));
      tm = fmaxf(tm, __shfl_xor(tm, 4));
      tm = fmaxf(tm, __shfl_xor(tm, 8));
      float nm = fmaxf(m_run[j], tm);
      alpha[j] = __expf(m_run[j] - nm);
      m_run[j] = nm;
    }
#pragma unroll
    for (int f = 0; f < 4; ++f)
#pragma unroll
      for (int j = 0; j < 4; ++j)
        sv[f][j] = __expf(sv[f][j] - m_run[j]);
#pragma unroll
    for (int j = 0; j < 4; ++j) {
      float ps = sv[0][j] + sv[1][j] + sv[2][j] + sv[3][j];
      ps += __shfl_xor(ps, 1); ps += __shfl_xor(ps, 2);
      ps += __shfl_xor(ps, 4); ps += __shfl_xor(ps, 8);
      s_run[j] = s_run[j] * alpha[j] + ps;
    }
#pragma unroll
    for (int f = 0; f < 4; ++f)
#pragma unroll
      for (int j = 0; j < 4; ++j)
        oacc[f][j] *= alpha[j];
    // ---- P -> LDS (bf16, A-layout source) ----
#pragma unroll
    for (int f = 0; f < 4; ++f)
#pragma unroll
      for (int j = 0; j < 4; ++j) {
        int r = (lane >> 4) * 4 + j;
        p_s[w][r][16 * f + (lane & 15)] = __float2bfloat16(sv[f][j]);
      }
    // ---- PV: O += P @ V ----
#pragma unroll
    for (int kk = 0; kk < 2; ++kk) {
      bf16x8 pf = *(const bf16x8*)&p_s[w][lane & 15][(lane >> 4) * 8 + 32 * kk];
#pragma unroll
      for (int f = 0; f < 4; ++f) {
        int d = 16 * f + (lane & 15);
        int cc = (lane >> 4) * 8 + 32 * kk;
        uint32_t byte = ((uint32_t)d << 7) + 2u * (uint32_t)cc;
        byte ^= (uint32_t)(((d & 7) ^ (d >> 3)) << 4);
        bf16x8 vf = *(const bf16x8*)((char*)vt_s + byte);
        oacc[f] = __builtin_amdgcn_mfma_f32_16x16x32_bf16(pf, vf, oacc[f], 0, 0, 0);
      }
    }
  }

  // ---- epilogue: O / s_run -> Y ----
#pragma unroll
  for (int f = 0; f < 4; ++f)
#pragma unroll
    for (int j = 0; j < 4; ++j) {
      int r = 16 * w + (lane >> 4) * 4 + j;
      int d = 16 * f + (lane & 15);
      float o = oacc[f][j] / s_run[j];
      Y[(size_t)(b * LL + l0 + r) * DD + h * 64 + d] = __float2bfloat16(o);
    }
}

// ---------------- launch ----------------
extern "C" void kernel_launch(void* const* d_in, const int* in_sizes, int n_in,
                              void* d_out, int out_size, void* d_ws, size_t ws_size,
                              hipStream_t stream) {
  (void)in_sizes; (void)n_in; (void)out_size; (void)ws_size;
  const float* x     = (const float*)d_in[0];
  const float* ln1w  = (const float*)d_in[1];
  const float* ln1b  = (const float*)d_in[2];
  const float* Wqkv  = (const float*)d_in[3];
  const float* bqkv  = (const float*)d_in[4];
  const float* Wproj = (const float*)d_in[5];
  const float* bproj = (const float*)d_in[6];
  const float* Er    = (const float*)d_in[7];
  const float* ln2w  = (const float*)d_in[8];
  const float* ln2b  = (const float*)d_in[9];
  const float* Wfc   = (const float*)d_in[10];
  const float* bfc   = (const float*)d_in[11];
  const float* Wfc2  = (const float*)d_in[12];
  const float* bfc2  = (const float*)d_in[13];
  float* out = (float*)d_out;

  char* ws = (char*)d_ws;
  const size_t MB = 1ull << 20;
  __hip_bfloat16* h1    = (__hip_bfloat16*)(ws + 0);        // 8 MB
  __hip_bfloat16* qkvb  = (__hip_bfloat16*)(ws + 8 * MB);   // 24 MB
  __hip_bfloat16* mbuf  = (__hip_bfloat16*)(ws + 0);        // 32 MB (aliases h1+qkvb)
  __hip_bfloat16* yb    = (__hip_bfloat16*)(ws + 32 * MB);  // 8 MB
  __hip_bfloat16* h2    = (__hip_bfloat16*)(ws + 32 * MB);  // 8 MB (aliases yb)
  float*          x2    = (float*)(ws + 40 * MB);           // 16 MB
  __hip_bfloat16* Wqkvt = (__hip_bfloat16*)(ws + 56 * MB);  // 6 MB
  __hip_bfloat16* Wprojt= (__hip_bfloat16*)(ws + 63 * MB);  // 2 MB
  __hip_bfloat16* Wfct  = (__hip_bfloat16*)(ws + 66 * MB);  // 8 MB
  __hip_bfloat16* Wfc2t = (__hip_bfloat16*)(ws + 75 * MB);  // 8 MB

  dim3 blk(256);

  transpose_cvt<<<dim3(3072 / 32, 1024 / 32), blk, 0, stream>>>(Wqkv, Wqkvt, 1024, 3072);
  transpose_cvt<<<dim3(1024 / 32, 1024 / 32), blk, 0, stream>>>(Wproj, Wprojt, 1024, 1024);
  transpose_cvt<<<dim3(4096 / 32, 1024 / 32), blk, 0, stream>>>(Wfc, Wfct, 1024, 4096);
  transpose_cvt<<<dim3(1024 / 32, 4096 / 32), blk, 0, stream>>>(Wfc2, Wfc2t, 4096, 1024);

  ln_kernel<<<4096, blk, 0, stream>>>(x, ln1w, ln1b, h1);

  gemm_bf16<0><<<dim3(3072 / 64, 4096 / 64), blk, 0, stream>>>(
      h1, Wqkvt, bqkv, nullptr, qkvb, 4096, 3072, 1024);

  attn_mfma<<<dim3(1024), blk, 0, stream>>>(qkvb, Er, yb);

  gemm_bf16<2><<<dim3(1024 / 64, 4096 / 64), blk, 0, stream>>>(
      yb, Wprojt, bproj, x, x2, 4096, 1024, 1024);

  ln_kernel<<<4096, blk, 0, stream>>>(x2, ln2w, ln2b, h2);

  gemm_bf16<1><<<dim3(4096 / 64, 4096 / 64), blk, 0, stream>>>(
      h2, Wfct, bfc, nullptr, mbuf, 4096, 4096, 1024);

  gemm_bf16<2><<<dim3(1024 / 64, 4096 / 64), blk, 0, stream>>>(
      mbuf, Wfc2t, bfc2, x2, out, 4096, 1024, 4096);
}

// Round 5
// 337.182 us; speedup vs baseline: 3.6827x; 1.0604x over previous
//
#include <hip/hip_runtime.h>
#include <hip/hip_bf16.h>
#include <math.h>

typedef __attribute__((ext_vector_type(8))) __bf16 bf16x8;
typedef __attribute__((ext_vector_type(4))) float f32x4;

#define LL 1024
#define DD 1024
#define HH 16

#define GLOAD16(g, l)                                              \
  __builtin_amdgcn_global_load_lds(                                \
      (const __attribute__((address_space(1))) void*)(g),          \
      (__attribute__((address_space(3))) void*)(l), 16, 0, 0)

// ---------------- weight transpose + fp32->bf16 ----------------
__global__ __launch_bounds__(256) void transpose_cvt(const float* __restrict__ W,
                                                     __hip_bfloat16* __restrict__ Wt,
                                                     int R, int C) {
  __shared__ float tile[32][33];
  int tx = threadIdx.x;
  int r0 = blockIdx.y * 32, c0 = blockIdx.x * 32;
  int r = tx >> 3, c4 = (tx & 7) * 4;
  float4 v = *(const float4*)&W[(size_t)(r0 + r) * C + c0 + c4];
  tile[r][c4 + 0] = v.x; tile[r][c4 + 1] = v.y;
  tile[r][c4 + 2] = v.z; tile[r][c4 + 3] = v.w;
  __syncthreads();
  int c = tx >> 3, r4 = (tx & 7) * 4;
  __hip_bfloat16 o[4];
#pragma unroll
  for (int j = 0; j < 4; ++j) o[j] = __float2bfloat16(tile[r4 + j][c]);
  *(uint2*)&Wt[(size_t)(c0 + c) * R + r0 + r4] = *(const uint2*)o;
}

// ---------------- layernorm (fp32 in -> bf16 out) ----------------
__global__ __launch_bounds__(256) void ln_kernel(const float* __restrict__ X,
                                                 const float* __restrict__ w,
                                                 const float* __restrict__ b,
                                                 __hip_bfloat16* __restrict__ out) {
  int row = blockIdx.x;
  int tid = threadIdx.x;
  const float* xr = X + (size_t)row * DD;
  float4 v = *(const float4*)&xr[tid * 4];
  float s = v.x + v.y + v.z + v.w;
  float s2 = v.x * v.x + v.y * v.y + v.z * v.z + v.w * v.w;
#pragma unroll
  for (int m = 1; m < 64; m <<= 1) {
    s += __shfl_xor(s, m);
    s2 += __shfl_xor(s2, m);
  }
  __shared__ float ps[4], ps2[4];
  int wv_ = tid >> 6, lane = tid & 63;
  if (lane == 0) { ps[wv_] = s; ps2[wv_] = s2; }
  __syncthreads();
  float ts = ps[0] + ps[1] + ps[2] + ps[3];
  float ts2 = ps2[0] + ps2[1] + ps2[2] + ps2[3];
  float mu = ts * (1.0f / DD);
  float var = ts2 * (1.0f / DD) - mu * mu;
  float rs = rsqrtf(var + 1e-5f);
  float4 wv = *(const float4*)&w[tid * 4];
  float4 bv = *(const float4*)&b[tid * 4];
  __hip_bfloat16 o[4];
  o[0] = __float2bfloat16((v.x - mu) * rs * wv.x + bv.x);
  o[1] = __float2bfloat16((v.y - mu) * rs * wv.y + bv.y);
  o[2] = __float2bfloat16((v.z - mu) * rs * wv.z + bv.z);
  o[3] = __float2bfloat16((v.w - mu) * rs * wv.w + bv.w);
  *(uint2*)&out[(size_t)row * DD + tid * 4] = *(const uint2*)o;
}

// ---------------- bf16 MFMA GEMM, 128x128 tile (m97 structure) ----------------
// C = A(MxK) * Bt(NxK)^T + bias;  EPI: 0 = bf16 out, 1 = GELU->bf16, 2 = fp32 + resid
template <int EPI>
__global__ __launch_bounds__(256) void gemm128(const __hip_bfloat16* __restrict__ A,
                                               const __hip_bfloat16* __restrict__ Bt,
                                               const float* __restrict__ bias,
                                               const float* __restrict__ resid,
                                               void* __restrict__ Cout,
                                               int M, int N, int K) {
  __shared__ __hip_bfloat16 a_lds[128][32];  // 8 KB, linear (gload_lds dest)
  __shared__ __hip_bfloat16 b_lds[128][32];  // 8 KB
  int tid = threadIdx.x, lane = tid & 63, w = tid >> 6;
  int bm0 = blockIdx.y * 128, bn0 = blockIdx.x * 128;
  int wr = w >> 1, wc = w & 1;
  const int fr = lane & 15, fk = (lane >> 4) * 8;

  // staging: wave w covers rows 32w..32w+31 of each tile; lane l -> row l/4, kcol (l%4)*8
  const __hip_bfloat16* aptr = A + (size_t)(bm0 + 32 * w + (lane >> 2)) * K + (lane & 3) * 8;
  const __hip_bfloat16* bptr = Bt + (size_t)(bn0 + 32 * w + (lane >> 2)) * K + (lane & 3) * 8;
  __hip_bfloat16* la0 = &a_lds[32 * w][0];
  __hip_bfloat16* la1 = &a_lds[32 * w + 16][0];
  __hip_bfloat16* lb0 = &b_lds[32 * w][0];
  __hip_bfloat16* lb1 = &b_lds[32 * w + 16][0];

  f32x4 acc[4][4] = {};

  for (int kk = 0; kk < K; kk += 32) {
    GLOAD16(aptr, la0);
    GLOAD16(aptr + (size_t)16 * K, la1);
    GLOAD16(bptr, lb0);
    GLOAD16(bptr + (size_t)16 * K, lb1);
    aptr += 32; bptr += 32;
    __syncthreads();  // drains vmcnt(0): staging visible
    bf16x8 af[4], bfv[4];
#pragma unroll
    for (int m = 0; m < 4; ++m) af[m] = *(const bf16x8*)&a_lds[64 * wr + 16 * m + fr][fk];
#pragma unroll
    for (int n = 0; n < 4; ++n) bfv[n] = *(const bf16x8*)&b_lds[64 * wc + 16 * n + fr][fk];
#pragma unroll
    for (int m = 0; m < 4; ++m)
#pragma unroll
      for (int n = 0; n < 4; ++n)
        acc[m][n] = __builtin_amdgcn_mfma_f32_16x16x32_bf16(af[m], bfv[n], acc[m][n], 0, 0, 0);
    __syncthreads();  // all reads done before next overwrite
  }

  // epilogue
#pragma unroll
  for (int n = 0; n < 4; ++n) {
    int col = bn0 + 64 * wc + 16 * n + fr;
    float bsv = bias[col];
#pragma unroll
    for (int m = 0; m < 4; ++m) {
      int rowb = bm0 + 64 * wr + 16 * m + (lane >> 4) * 4;
#pragma unroll
      for (int j = 0; j < 4; ++j) {
        int row = rowb + j;
        float v = acc[m][n][j] + bsv;
        if (EPI == 1) v = 0.5f * v * (1.0f + erff(v * 0.7071067811865476f));
        if (EPI == 2) {
          ((float*)Cout)[(size_t)row * N + col] = v + resid[(size_t)row * N + col];
        } else {
          ((__hip_bfloat16*)Cout)[(size_t)row * N + col] = __float2bfloat16(v);
        }
      }
    }
  }
}

// ---------------- MFMA flash attention with relative-position skew ----------------
__global__ __launch_bounds__(256) void attn_mfma(const __hip_bfloat16* __restrict__ qkv,
                                                 const float* __restrict__ Er,
                                                 __hip_bfloat16* __restrict__ Y) {
  __shared__ __hip_bfloat16 q_s[64][72];
  __shared__ __hip_bfloat16 k_s[64][72];
  __shared__ __hip_bfloat16 er_s[128][72];
  __shared__ __hip_bfloat16 p_s[4][16][72];
  __shared__ __hip_bfloat16 g_s[4][16][136];
  __shared__ __hip_bfloat16 vt_s[64 * 64];  // transposed V, XOR-swizzled

  int bid = blockIdx.x;
  int qi = 15 - (bid >> 6);
  int head = bid & 63;
  int h = head & 15, b = head >> 4;
  int l0 = qi * 64;
  int tid = threadIdx.x, lane = tid & 63, w = tid >> 6;

  const __hip_bfloat16* base = qkv + (size_t)b * (LL * 3072) + h * 64;

  {
    int r = tid >> 2, d0 = (tid & 3) * 16;
    const __hip_bfloat16* src = base + (size_t)(l0 + r) * 3072 + d0;
    *(uint4*)&q_s[r][d0] = *(const uint4*)src;
    *(uint4*)&q_s[r][d0 + 8] = *(const uint4*)(src + 8);
  }
  __syncthreads();
  bf16x8 qf[2];
  {
    int r = 16 * w + (lane & 15), kc = (lane >> 4) * 8;
    qf[0] = *(const bf16x8*)&q_s[r][kc];
    qf[1] = *(const bf16x8*)&q_s[r][kc + 32];
  }

  f32x4 oacc[4] = {};
  float m_run[4], s_run[4];
#pragma unroll
  for (int j = 0; j < 4; ++j) { m_run[j] = -1e30f; s_run[j] = 0.f; }

  for (int t = 0; t <= qi; ++t) {
    int c0 = t * 64;
    __syncthreads();
    {
      int r = tid >> 2, d0 = (tid & 3) * 16;
      const __hip_bfloat16* src = base + 1024 + (size_t)(c0 + r) * 3072 + d0;
      *(uint4*)&k_s[r][d0] = *(const uint4*)src;
      *(uint4*)&k_s[r][d0 + 8] = *(const uint4*)(src + 8);
    }
    {
      int c = (tid >> 3) * 2, d0 = (tid & 7) * 8;
      const __hip_bfloat16* s0 = base + 2048 + (size_t)(c0 + c) * 3072 + d0;
      uint4 u0 = *(const uint4*)s0;
      uint4 u1 = *(const uint4*)(s0 + 3072);
      const uint16_t* h0 = (const uint16_t*)&u0;
      const uint16_t* h1 = (const uint16_t*)&u1;
#pragma unroll
      for (int j = 0; j < 8; ++j) {
        int d = d0 + j;
        uint32_t pk = (uint32_t)h0[j] | ((uint32_t)h1[j] << 16);
        uint32_t byte = ((uint32_t)d << 7) + 2u * (uint32_t)c;
        byte ^= (uint32_t)(((d & 7) ^ (d >> 3)) << 4);
        *(uint32_t*)((char*)vt_s + byte) = pk;
      }
    }
    {
      int jj = tid >> 1, ch = (tid & 1) * 32;
      int m = 960 + c0 - l0 + jj;
      m = min(max(m, 0), 1023);
      const float* src = Er + (size_t)m * 64 + ch;
#pragma unroll
      for (int i = 0; i < 8; ++i) {
        float4 v = *(const float4*)(src + 4 * i);
        __hip_bfloat16 o[4];
        o[0] = __float2bfloat16(v.x); o[1] = __float2bfloat16(v.y);
        o[2] = __float2bfloat16(v.z); o[3] = __float2bfloat16(v.w);
        *(uint2*)&er_s[jj][ch + 4 * i] = *(const uint2*)o;
      }
    }
    __syncthreads();

    f32x4 sacc[4] = {};
#pragma unroll
    for (int f = 0; f < 4; ++f) {
      int cc = 16 * f + (lane & 15), kc = (lane >> 4) * 8;
      bf16x8 k0 = *(const bf16x8*)&k_s[cc][kc];
      bf16x8 k1 = *(const bf16x8*)&k_s[cc][kc + 32];
      sacc[f] = __builtin_amdgcn_mfma_f32_16x16x32_bf16(qf[0], k0, sacc[f], 0, 0, 0);
      sacc[f] = __builtin_amdgcn_mfma_f32_16x16x32_bf16(qf[1], k1, sacc[f], 0, 0, 0);
    }
#pragma unroll
    for (int g = 0; g < 8; ++g) {
      int cc = 16 * g + (lane & 15), kc = (lane >> 4) * 8;
      bf16x8 e0 = *(const bf16x8*)&er_s[cc][kc];
      bf16x8 e1 = *(const bf16x8*)&er_s[cc][kc + 32];
      f32x4 gacc = {};
      gacc = __builtin_amdgcn_mfma_f32_16x16x32_bf16(qf[0], e0, gacc, 0, 0, 0);
      gacc = __builtin_amdgcn_mfma_f32_16x16x32_bf16(qf[1], e1, gacc, 0, 0, 0);
#pragma unroll
      for (int j = 0; j < 4; ++j) {
        int r = (lane >> 4) * 4 + j;
        g_s[w][r][16 * g + (lane & 15)] = __float2bfloat16(gacc[j]);
      }
    }

    float sv[4][4];
#pragma unroll
    for (int f = 0; f < 4; ++f) {
#pragma unroll
      for (int j = 0; j < 4; ++j) {
        int r = (lane >> 4) * 4 + j;
        int c = 16 * f + (lane & 15);
        int jj = c - (16 * w + r) + 63;
        float g = __bfloat162float(g_s[w][r][jj]);
        float val = (sacc[f][j] + g) * 0.125f;
        if (t == qi && c > 16 * w + r) val = -1e30f;
        sv[f][j] = val;
      }
    }
    float alpha[4];
#pragma unroll
    for (int j = 0; j < 4; ++j) {
      float tm = fmaxf(fmaxf(sv[0][j], sv[1][j]), fmaxf(sv[2][j], sv[3][j]));
      tm = fmaxf(tm, __shfl_xor(tm, 1));
      tm = fmaxf(tm, __shfl_xor(tm, 2));
      tm = fmaxf(tm, __shfl_xor(tm, 4));
      tm = fmaxf(tm, __shfl_xor(tm, 8));
      float nm = fmaxf(m_run[j], tm);
      alpha[j] = __expf(m_run[j] - nm);
      m_run[j] = nm;
    }
#pragma unroll
    for (int f = 0; f < 4; ++f)
#pragma unroll
      for (int j = 0; j < 4; ++j)
        sv[f][j] = __expf(sv[f][j] - m_run[j]);
#pragma unroll
    for (int j = 0; j < 4; ++j) {
      float ps = sv[0][j] + sv[1][j] + sv[2][j] + sv[3][j];
      ps += __shfl_xor(ps, 1); ps += __shfl_xor(ps, 2);
      ps += __shfl_xor(ps, 4); ps += __shfl_xor(ps, 8);
      s_run[j] = s_run[j] * alpha[j] + ps;
    }
#pragma unroll
    for (int f = 0; f < 4; ++f)
#pragma unroll
      for (int j = 0; j < 4; ++j)
        oacc[f][j] *= alpha[j];
#pragma unroll
    for (int f = 0; f < 4; ++f)
#pragma unroll
      for (int j = 0; j < 4; ++j) {
        int r = (lane >> 4) * 4 + j;
        p_s[w][r][16 * f + (lane & 15)] = __float2bfloat16(sv[f][j]);
      }
#pragma unroll
    for (int kk = 0; kk < 2; ++kk) {
      bf16x8 pf = *(const bf16x8*)&p_s[w][lane & 15][(lane >> 4) * 8 + 32 * kk];
#pragma unroll
      for (int f = 0; f < 4; ++f) {
        int d = 16 * f + (lane & 15);
        int cc = (lane >> 4) * 8 + 32 * kk;
        uint32_t byte = ((uint32_t)d << 7) + 2u * (uint32_t)cc;
        byte ^= (uint32_t)(((d & 7) ^ (d >> 3)) << 4);
        bf16x8 vf = *(const bf16x8*)((char*)vt_s + byte);
        oacc[f] = __builtin_amdgcn_mfma_f32_16x16x32_bf16(pf, vf, oacc[f], 0, 0, 0);
      }
    }
  }

#pragma unroll
  for (int f = 0; f < 4; ++f)
#pragma unroll
    for (int j = 0; j < 4; ++j) {
      int r = 16 * w + (lane >> 4) * 4 + j;
      int d = 16 * f + (lane & 15);
      float o = oacc[f][j] / s_run[j];
      Y[(size_t)(b * LL + l0 + r) * DD + h * 64 + d] = __float2bfloat16(o);
    }
}

// ---------------- launch ----------------
extern "C" void kernel_launch(void* const* d_in, const int* in_sizes, int n_in,
                              void* d_out, int out_size, void* d_ws, size_t ws_size,
                              hipStream_t stream) {
  (void)in_sizes; (void)n_in; (void)out_size; (void)ws_size;
  const float* x     = (const float*)d_in[0];
  const float* ln1w  = (const float*)d_in[1];
  const float* ln1b  = (const float*)d_in[2];
  const float* Wqkv  = (const float*)d_in[3];
  const float* bqkv  = (const float*)d_in[4];
  const float* Wproj = (const float*)d_in[5];
  const float* bproj = (const float*)d_in[6];
  const float* Er    = (const float*)d_in[7];
  const float* ln2w  = (const float*)d_in[8];
  const float* ln2b  = (const float*)d_in[9];
  const float* Wfc   = (const float*)d_in[10];
  const float* bfc   = (const float*)d_in[11];
  const float* Wfc2  = (const float*)d_in[12];
  const float* bfc2  = (const float*)d_in[13];
  float* out = (float*)d_out;

  char* ws = (char*)d_ws;
  const size_t MB = 1ull << 20;
  __hip_bfloat16* h1    = (__hip_bfloat16*)(ws + 0);        // 8 MB
  __hip_bfloat16* qkvb  = (__hip_bfloat16*)(ws + 8 * MB);   // 24 MB
  __hip_bfloat16* mbuf  = (__hip_bfloat16*)(ws + 0);        // 32 MB (aliases h1+qkvb)
  __hip_bfloat16* yb    = (__hip_bfloat16*)(ws + 32 * MB);  // 8 MB
  __hip_bfloat16* h2    = (__hip_bfloat16*)(ws + 32 * MB);  // 8 MB (aliases yb)
  float*          x2    = (float*)(ws + 40 * MB);           // 16 MB
  __hip_bfloat16* Wqkvt = (__hip_bfloat16*)(ws + 56 * MB);  // 6 MB
  __hip_bfloat16* Wprojt= (__hip_bfloat16*)(ws + 63 * MB);  // 2 MB
  __hip_bfloat16* Wfct  = (__hip_bfloat16*)(ws + 66 * MB);  // 8 MB
  __hip_bfloat16* Wfc2t = (__hip_bfloat16*)(ws + 75 * MB);  // 8 MB

  dim3 blk(256);

  transpose_cvt<<<dim3(3072 / 32, 1024 / 32), blk, 0, stream>>>(Wqkv, Wqkvt, 1024, 3072);
  transpose_cvt<<<dim3(1024 / 32, 1024 / 32), blk, 0, stream>>>(Wproj, Wprojt, 1024, 1024);
  transpose_cvt<<<dim3(4096 / 32, 1024 / 32), blk, 0, stream>>>(Wfc, Wfct, 1024, 4096);
  transpose_cvt<<<dim3(1024 / 32, 4096 / 32), blk, 0, stream>>>(Wfc2, Wfc2t, 4096, 1024);

  ln_kernel<<<4096, blk, 0, stream>>>(x, ln1w, ln1b, h1);

  gemm128<0><<<dim3(3072 / 128, 4096 / 128), blk, 0, stream>>>(
      h1, Wqkvt, bqkv, nullptr, qkvb, 4096, 3072, 1024);

  attn_mfma<<<dim3(1024), blk, 0, stream>>>(qkvb, Er, yb);

  gemm128<2><<<dim3(1024 / 128, 4096 / 128), blk, 0, stream>>>(
      yb, Wprojt, bproj, x, x2, 4096, 1024, 1024);

  ln_kernel<<<4096, blk, 0, stream>>>(x2, ln2w, ln2b, h2);

  gemm128<1><<<dim3(4096 / 128, 4096 / 128), blk, 0, stream>>>(
      h2, Wfct, bfc, nullptr, mbuf, 4096, 4096, 1024);

  gemm128<2><<<dim3(1024 / 128, 4096 / 128), blk, 0, stream>>>(
      mbuf, Wfc2t, bfc2, x2, out, 4096, 1024, 4096);
}

// Round 6
// 316.830 us; speedup vs baseline: 3.9193x; 1.0642x over previous
//
#include <hip/hip_runtime.h>
#include <hip/hip_bf16.h>
#include <math.h>

typedef __attribute__((ext_vector_type(8))) __bf16 bf16x8;
typedef __attribute__((ext_vector_type(4))) float f32x4;

#define LL 1024
#define DD 1024
#define HH 16

#define GLOAD16(g, l)                                              \
  __builtin_amdgcn_global_load_lds(                                \
      (const __attribute__((address_space(1))) void*)(g),          \
      (__attribute__((address_space(3))) void*)(l), 16, 0, 0)

// ---------------- weight transpose + fp32->bf16 ----------------
__global__ __launch_bounds__(256) void transpose_cvt(const float* __restrict__ W,
                                                     __hip_bfloat16* __restrict__ Wt,
                                                     int R, int C) {
  __shared__ float tile[32][33];
  int tx = threadIdx.x;
  int r0 = blockIdx.y * 32, c0 = blockIdx.x * 32;
  int r = tx >> 3, c4 = (tx & 7) * 4;
  float4 v = *(const float4*)&W[(size_t)(r0 + r) * C + c0 + c4];
  tile[r][c4 + 0] = v.x; tile[r][c4 + 1] = v.y;
  tile[r][c4 + 2] = v.z; tile[r][c4 + 3] = v.w;
  __syncthreads();
  int c = tx >> 3, r4 = (tx & 7) * 4;
  __hip_bfloat16 o[4];
#pragma unroll
  for (int j = 0; j < 4; ++j) o[j] = __float2bfloat16(tile[r4 + j][c]);
  *(uint2*)&Wt[(size_t)(c0 + c) * R + r0 + r4] = *(const uint2*)o;
}

// ---------------- layernorm (fp32 in -> bf16 out) ----------------
__global__ __launch_bounds__(256) void ln_kernel(const float* __restrict__ X,
                                                 const float* __restrict__ w,
                                                 const float* __restrict__ b,
                                                 __hip_bfloat16* __restrict__ out) {
  int row = blockIdx.x;
  int tid = threadIdx.x;
  const float* xr = X + (size_t)row * DD;
  float4 v = *(const float4*)&xr[tid * 4];
  float s = v.x + v.y + v.z + v.w;
  float s2 = v.x * v.x + v.y * v.y + v.z * v.z + v.w * v.w;
#pragma unroll
  for (int m = 1; m < 64; m <<= 1) {
    s += __shfl_xor(s, m);
    s2 += __shfl_xor(s2, m);
  }
  __shared__ float ps[4], ps2[4];
  int wv_ = tid >> 6, lane = tid & 63;
  if (lane == 0) { ps[wv_] = s; ps2[wv_] = s2; }
  __syncthreads();
  float ts = ps[0] + ps[1] + ps[2] + ps[3];
  float ts2 = ps2[0] + ps2[1] + ps2[2] + ps2[3];
  float mu = ts * (1.0f / DD);
  float var = ts2 * (1.0f / DD) - mu * mu;
  float rs = rsqrtf(var + 1e-5f);
  float4 wv = *(const float4*)&w[tid * 4];
  float4 bv = *(const float4*)&b[tid * 4];
  __hip_bfloat16 o[4];
  o[0] = __float2bfloat16((v.x - mu) * rs * wv.x + bv.x);
  o[1] = __float2bfloat16((v.y - mu) * rs * wv.y + bv.y);
  o[2] = __float2bfloat16((v.z - mu) * rs * wv.z + bv.z);
  o[3] = __float2bfloat16((v.w - mu) * rs * wv.w + bv.w);
  *(uint2*)&out[(size_t)row * DD + tid * 4] = *(const uint2*)o;
}

// ---------------- bf16 MFMA GEMM, 128x128 tile, 2-phase dbuf prefetch ----------------
// C = A(MxK) * Bt(NxK)^T + bias;  EPI: 0 = bf16 out, 1 = GELU->bf16, 2 = fp32 + resid
template <int EPI>
__global__ __launch_bounds__(256) void gemm128(const __hip_bfloat16* __restrict__ A,
                                               const __hip_bfloat16* __restrict__ Bt,
                                               const float* __restrict__ bias,
                                               const float* __restrict__ resid,
                                               void* __restrict__ Cout,
                                               int M, int N, int K) {
  __shared__ __hip_bfloat16 a_lds[2][128][32];  // 2 x 8 KB
  __shared__ __hip_bfloat16 b_lds[2][128][32];
  int tid = threadIdx.x, lane = tid & 63, w = tid >> 6;

  // XCD-aware bijective swizzle (grids here are all % 8 == 0)
  int nbx = gridDim.x, nwg = nbx * gridDim.y;
  int orig = blockIdx.y * nbx + blockIdx.x;
  int cpx = nwg >> 3;
  int wgid = (orig & 7) * cpx + (orig >> 3);
  int bm0 = (wgid / nbx) * 128, bn0 = (wgid % nbx) * 128;

  int wr = w >> 1, wc = w & 1;
  const int fr = lane & 15, fk = (lane >> 4) * 8;

  // staging: wave w covers rows 32w..32w+31; lane l -> row l/4, kcol (l%4)*8
  const __hip_bfloat16* aptr = A + (size_t)(bm0 + 32 * w + (lane >> 2)) * K + (lane & 3) * 8;
  const __hip_bfloat16* bptr = Bt + (size_t)(bn0 + 32 * w + (lane >> 2)) * K + (lane & 3) * 8;

  f32x4 acc[4][4] = {};

  // prologue: stage K-step 0 into buf 0
  GLOAD16(aptr, &a_lds[0][32 * w][0]);
  GLOAD16(aptr + (size_t)16 * K, &a_lds[0][32 * w + 16][0]);
  GLOAD16(bptr, &b_lds[0][32 * w][0]);
  GLOAD16(bptr + (size_t)16 * K, &b_lds[0][32 * w + 16][0]);
  aptr += 32; bptr += 32;
  __syncthreads();  // vmcnt(0) drain + barrier: buf0 ready

  int cur = 0;
  for (int kk = 32; kk <= K; kk += 32) {
    // phase A: issue next K-step's staging into the other buffer
    if (kk < K) {
      int nxt = cur ^ 1;
      GLOAD16(aptr, &a_lds[nxt][32 * w][0]);
      GLOAD16(aptr + (size_t)16 * K, &a_lds[nxt][32 * w + 16][0]);
      GLOAD16(bptr, &b_lds[nxt][32 * w][0]);
      GLOAD16(bptr + (size_t)16 * K, &b_lds[nxt][32 * w + 16][0]);
      aptr += 32; bptr += 32;
    }
    // phase B: compute current buffer (HBM latency of phase A hides under this)
    bf16x8 af[4], bfv[4];
#pragma unroll
    for (int m = 0; m < 4; ++m)
      af[m] = *(const bf16x8*)&a_lds[cur][64 * wr + 16 * m + fr][fk];
#pragma unroll
    for (int n = 0; n < 4; ++n)
      bfv[n] = *(const bf16x8*)&b_lds[cur][64 * wc + 16 * n + fr][fk];
#pragma unroll
    for (int m = 0; m < 4; ++m)
#pragma unroll
      for (int n = 0; n < 4; ++n)
        acc[m][n] = __builtin_amdgcn_mfma_f32_16x16x32_bf16(af[m], bfv[n], acc[m][n], 0, 0, 0);
    __syncthreads();  // drains vmcnt(0): next buffer staged; all reads of cur done
    cur ^= 1;
  }

  // epilogue
#pragma unroll
  for (int n = 0; n < 4; ++n) {
    int col = bn0 + 64 * wc + 16 * n + fr;
    float bsv = bias[col];
#pragma unroll
    for (int m = 0; m < 4; ++m) {
      int rowb = bm0 + 64 * wr + 16 * m + (lane >> 4) * 4;
#pragma unroll
      for (int j = 0; j < 4; ++j) {
        int row = rowb + j;
        float v = acc[m][n][j] + bsv;
        if (EPI == 1) v = 0.5f * v * (1.0f + erff(v * 0.7071067811865476f));
        if (EPI == 2) {
          ((float*)Cout)[(size_t)row * N + col] = v + resid[(size_t)row * N + col];
        } else {
          ((__hip_bfloat16*)Cout)[(size_t)row * N + col] = __float2bfloat16(v);
        }
      }
    }
  }
}

// ---------------- MFMA flash attention with relative-position skew ----------------
__global__ __launch_bounds__(256) void attn_mfma(const __hip_bfloat16* __restrict__ qkv,
                                                 const float* __restrict__ Er,
                                                 __hip_bfloat16* __restrict__ Y) {
  __shared__ __hip_bfloat16 q_s[64][72];
  __shared__ __hip_bfloat16 k_s[64][72];
  __shared__ __hip_bfloat16 er_s[128][72];
  __shared__ __hip_bfloat16 p_s[4][16][72];
  __shared__ __hip_bfloat16 g_s[4][16][136];
  __shared__ __hip_bfloat16 vt_s[64 * 64];  // transposed V, XOR-swizzled

  int bid = blockIdx.x;
  int qi = 15 - (bid >> 6);
  int head = bid & 63;
  int h = head & 15, b = head >> 4;
  int l0 = qi * 64;
  int tid = threadIdx.x, lane = tid & 63, w = tid >> 6;

  const __hip_bfloat16* base = qkv + (size_t)b * (LL * 3072) + h * 64;

  {
    int r = tid >> 2, d0 = (tid & 3) * 16;
    const __hip_bfloat16* src = base + (size_t)(l0 + r) * 3072 + d0;
    *(uint4*)&q_s[r][d0] = *(const uint4*)src;
    *(uint4*)&q_s[r][d0 + 8] = *(const uint4*)(src + 8);
  }
  __syncthreads();
  bf16x8 qf[2];
  {
    int r = 16 * w + (lane & 15), kc = (lane >> 4) * 8;
    qf[0] = *(const bf16x8*)&q_s[r][kc];
    qf[1] = *(const bf16x8*)&q_s[r][kc + 32];
  }

  f32x4 oacc[4] = {};
  float m_run[4], s_run[4];
#pragma unroll
  for (int j = 0; j < 4; ++j) { m_run[j] = -1e30f; s_run[j] = 0.f; }

  for (int t = 0; t <= qi; ++t) {
    int c0 = t * 64;
    __syncthreads();
    {
      int r = tid >> 2, d0 = (tid & 3) * 16;
      const __hip_bfloat16* src = base + 1024 + (size_t)(c0 + r) * 3072 + d0;
      *(uint4*)&k_s[r][d0] = *(const uint4*)src;
      *(uint4*)&k_s[r][d0 + 8] = *(const uint4*)(src + 8);
    }
    {
      int c = (tid >> 3) * 2, d0 = (tid & 7) * 8;
      const __hip_bfloat16* s0 = base + 2048 + (size_t)(c0 + c) * 3072 + d0;
      uint4 u0 = *(const uint4*)s0;
      uint4 u1 = *(const uint4*)(s0 + 3072);
      const uint16_t* h0 = (const uint16_t*)&u0;
      const uint16_t* h1 = (const uint16_t*)&u1;
#pragma unroll
      for (int j = 0; j < 8; ++j) {
        int d = d0 + j;
        uint32_t pk = (uint32_t)h0[j] | ((uint32_t)h1[j] << 16);
        uint32_t byte = ((uint32_t)d << 7) + 2u * (uint32_t)c;
        byte ^= (uint32_t)(((d & 7) ^ (d >> 3)) << 4);
        *(uint32_t*)((char*)vt_s + byte) = pk;
      }
    }
    {
      int jj = tid >> 1, ch = (tid & 1) * 32;
      int m = 960 + c0 - l0 + jj;
      m = min(max(m, 0), 1023);
      const float* src = Er + (size_t)m * 64 + ch;
#pragma unroll
      for (int i = 0; i < 8; ++i) {
        float4 v = *(const float4*)(src + 4 * i);
        __hip_bfloat16 o[4];
        o[0] = __float2bfloat16(v.x); o[1] = __float2bfloat16(v.y);
        o[2] = __float2bfloat16(v.z); o[3] = __float2bfloat16(v.w);
        *(uint2*)&er_s[jj][ch + 4 * i] = *(const uint2*)o;
      }
    }
    __syncthreads();

    f32x4 sacc[4] = {};
#pragma unroll
    for (int f = 0; f < 4; ++f) {
      int cc = 16 * f + (lane & 15), kc = (lane >> 4) * 8;
      bf16x8 k0 = *(const bf16x8*)&k_s[cc][kc];
      bf16x8 k1 = *(const bf16x8*)&k_s[cc][kc + 32];
      sacc[f] = __builtin_amdgcn_mfma_f32_16x16x32_bf16(qf[0], k0, sacc[f], 0, 0, 0);
      sacc[f] = __builtin_amdgcn_mfma_f32_16x16x32_bf16(qf[1], k1, sacc[f], 0, 0, 0);
    }
#pragma unroll
    for (int g = 0; g < 8; ++g) {
      int cc = 16 * g + (lane & 15), kc = (lane >> 4) * 8;
      bf16x8 e0 = *(const bf16x8*)&er_s[cc][kc];
      bf16x8 e1 = *(const bf16x8*)&er_s[cc][kc + 32];
      f32x4 gacc = {};
      gacc = __builtin_amdgcn_mfma_f32_16x16x32_bf16(qf[0], e0, gacc, 0, 0, 0);
      gacc = __builtin_amdgcn_mfma_f32_16x16x32_bf16(qf[1], e1, gacc, 0, 0, 0);
#pragma unroll
      for (int j = 0; j < 4; ++j) {
        int r = (lane >> 4) * 4 + j;
        g_s[w][r][16 * g + (lane & 15)] = __float2bfloat16(gacc[j]);
      }
    }

    float sv[4][4];
#pragma unroll
    for (int f = 0; f < 4; ++f) {
#pragma unroll
      for (int j = 0; j < 4; ++j) {
        int r = (lane >> 4) * 4 + j;
        int c = 16 * f + (lane & 15);
        int jj = c - (16 * w + r) + 63;
        float g = __bfloat162float(g_s[w][r][jj]);
        float val = (sacc[f][j] + g) * 0.125f;
        if (t == qi && c > 16 * w + r) val = -1e30f;
        sv[f][j] = val;
      }
    }
    float alpha[4];
#pragma unroll
    for (int j = 0; j < 4; ++j) {
      float tm = fmaxf(fmaxf(sv[0][j], sv[1][j]), fmaxf(sv[2][j], sv[3][j]));
      tm = fmaxf(tm, __shfl_xor(tm, 1));
      tm = fmaxf(tm, __shfl_xor(tm, 2));
      tm = fmaxf(tm, __shfl_xor(tm, 4));
      tm = fmaxf(tm, __shfl_xor(tm, 8));
      float nm = fmaxf(m_run[j], tm);
      alpha[j] = __expf(m_run[j] - nm);
      m_run[j] = nm;
    }
#pragma unroll
    for (int f = 0; f < 4; ++f)
#pragma unroll
      for (int j = 0; j < 4; ++j)
        sv[f][j] = __expf(sv[f][j] - m_run[j]);
#pragma unroll
    for (int j = 0; j < 4; ++j) {
      float ps = sv[0][j] + sv[1][j] + sv[2][j] + sv[3][j];
      ps += __shfl_xor(ps, 1); ps += __shfl_xor(ps, 2);
      ps += __shfl_xor(ps, 4); ps += __shfl_xor(ps, 8);
      s_run[j] = s_run[j] * alpha[j] + ps;
    }
#pragma unroll
    for (int f = 0; f < 4; ++f)
#pragma unroll
      for (int j = 0; j < 4; ++j)
        oacc[f][j] *= alpha[j];
#pragma unroll
    for (int f = 0; f < 4; ++f)
#pragma unroll
      for (int j = 0; j < 4; ++j) {
        int r = (lane >> 4) * 4 + j;
        p_s[w][r][16 * f + (lane & 15)] = __float2bfloat16(sv[f][j]);
      }
#pragma unroll
    for (int kk = 0; kk < 2; ++kk) {
      bf16x8 pf = *(const bf16x8*)&p_s[w][lane & 15][(lane >> 4) * 8 + 32 * kk];
#pragma unroll
      for (int f = 0; f < 4; ++f) {
        int d = 16 * f + (lane & 15);
        int cc = (lane >> 4) * 8 + 32 * kk;
        uint32_t byte = ((uint32_t)d << 7) + 2u * (uint32_t)cc;
        byte ^= (uint32_t)(((d & 7) ^ (d >> 3)) << 4);
        bf16x8 vf = *(const bf16x8*)((char*)vt_s + byte);
        oacc[f] = __builtin_amdgcn_mfma_f32_16x16x32_bf16(pf, vf, oacc[f], 0, 0, 0);
      }
    }
  }

#pragma unroll
  for (int f = 0; f < 4; ++f)
#pragma unroll
    for (int j = 0; j < 4; ++j) {
      int r = 16 * w + (lane >> 4) * 4 + j;
      int d = 16 * f + (lane & 15);
      float o = oacc[f][j] / s_run[j];
      Y[(size_t)(b * LL + l0 + r) * DD + h * 64 + d] = __float2bfloat16(o);
    }
}

// ---------------- launch ----------------
extern "C" void kernel_launch(void* const* d_in, const int* in_sizes, int n_in,
                              void* d_out, int out_size, void* d_ws, size_t ws_size,
                              hipStream_t stream) {
  (void)in_sizes; (void)n_in; (void)out_size; (void)ws_size;
  const float* x     = (const float*)d_in[0];
  const float* ln1w  = (const float*)d_in[1];
  const float* ln1b  = (const float*)d_in[2];
  const float* Wqkv  = (const float*)d_in[3];
  const float* bqkv  = (const float*)d_in[4];
  const float* Wproj = (const float*)d_in[5];
  const float* bproj = (const float*)d_in[6];
  const float* Er    = (const float*)d_in[7];
  const float* ln2w  = (const float*)d_in[8];
  const float* ln2b  = (const float*)d_in[9];
  const float* Wfc   = (const float*)d_in[10];
  const float* bfc   = (const float*)d_in[11];
  const float* Wfc2  = (const float*)d_in[12];
  const float* bfc2  = (const float*)d_in[13];
  float* out = (float*)d_out;

  char* ws = (char*)d_ws;
  const size_t MB = 1ull << 20;
  __hip_bfloat16* h1    = (__hip_bfloat16*)(ws + 0);        // 8 MB
  __hip_bfloat16* qkvb  = (__hip_bfloat16*)(ws + 8 * MB);   // 24 MB
  __hip_bfloat16* mbuf  = (__hip_bfloat16*)(ws + 0);        // 32 MB (aliases h1+qkvb)
  __hip_bfloat16* yb    = (__hip_bfloat16*)(ws + 32 * MB);  // 8 MB
  __hip_bfloat16* h2    = (__hip_bfloat16*)(ws + 32 * MB);  // 8 MB (aliases yb)
  float*          x2    = (float*)(ws + 40 * MB);           // 16 MB
  __hip_bfloat16* Wqkvt = (__hip_bfloat16*)(ws + 56 * MB);  // 6 MB
  __hip_bfloat16* Wprojt= (__hip_bfloat16*)(ws + 63 * MB);  // 2 MB
  __hip_bfloat16* Wfct  = (__hip_bfloat16*)(ws + 66 * MB);  // 8 MB
  __hip_bfloat16* Wfc2t = (__hip_bfloat16*)(ws + 75 * MB);  // 8 MB

  dim3 blk(256);

  transpose_cvt<<<dim3(3072 / 32, 1024 / 32), blk, 0, stream>>>(Wqkv, Wqkvt, 1024, 3072);
  transpose_cvt<<<dim3(1024 / 32, 1024 / 32), blk, 0, stream>>>(Wproj, Wprojt, 1024, 1024);
  transpose_cvt<<<dim3(4096 / 32, 1024 / 32), blk, 0, stream>>>(Wfc, Wfct, 1024, 4096);
  transpose_cvt<<<dim3(1024 / 32, 4096 / 32), blk, 0, stream>>>(Wfc2, Wfc2t, 4096, 1024);

  ln_kernel<<<4096, blk, 0, stream>>>(x, ln1w, ln1b, h1);

  gemm128<0><<<dim3(3072 / 128, 4096 / 128), blk, 0, stream>>>(
      h1, Wqkvt, bqkv, nullptr, qkvb, 4096, 3072, 1024);

  attn_mfma<<<dim3(1024), blk, 0, stream>>>(qkvb, Er, yb);

  gemm128<2><<<dim3(1024 / 128, 4096 / 128), blk, 0, stream>>>(
      yb, Wprojt, bproj, x, x2, 4096, 1024, 1024);

  ln_kernel<<<4096, blk, 0, stream>>>(x2, ln2w, ln2b, h2);

  gemm128<1><<<dim3(4096 / 128, 4096 / 128), blk, 0, stream>>>(
      h2, Wfct, bfc, nullptr, mbuf, 4096, 4096, 1024);

  gemm128<2><<<dim3(1024 / 128, 4096 / 128), blk, 0, stream>>>(
      mbuf, Wfc2t, bfc2, x2, out, 4096, 1024, 4096);
}

// Round 7
// 297.081 us; speedup vs baseline: 4.1798x; 1.0665x over previous
//
#include <hip/hip_runtime.h>
#include <hip/hip_bf16.h>
#include <math.h>

typedef __attribute__((ext_vector_type(8))) __bf16 bf16x8;
typedef __attribute__((ext_vector_type(4))) float f32x4;

#define LL 1024
#define DD 1024
#define HH 16

#define GLOAD16(g, l)                                              \
  __builtin_amdgcn_global_load_lds(                                \
      (const __attribute__((address_space(1))) void*)(g),          \
      (__attribute__((address_space(3))) void*)(l), 16, 0, 0)

// ---------------- weight transpose + fp32->bf16 ----------------
__global__ __launch_bounds__(256) void transpose_cvt(const float* __restrict__ W,
                                                     __hip_bfloat16* __restrict__ Wt,
                                                     int R, int C) {
  __shared__ float tile[32][33];
  int tx = threadIdx.x;
  int r0 = blockIdx.y * 32, c0 = blockIdx.x * 32;
  int r = tx >> 3, c4 = (tx & 7) * 4;
  float4 v = *(const float4*)&W[(size_t)(r0 + r) * C + c0 + c4];
  tile[r][c4 + 0] = v.x; tile[r][c4 + 1] = v.y;
  tile[r][c4 + 2] = v.z; tile[r][c4 + 3] = v.w;
  __syncthreads();
  int c = tx >> 3, r4 = (tx & 7) * 4;
  __hip_bfloat16 o[4];
#pragma unroll
  for (int j = 0; j < 4; ++j) o[j] = __float2bfloat16(tile[r4 + j][c]);
  *(uint2*)&Wt[(size_t)(c0 + c) * R + r0 + r4] = *(const uint2*)o;
}

// ---------------- Er fp32 -> bf16 (once) ----------------
__global__ __launch_bounds__(256) void cvt_er(const float* __restrict__ Er,
                                              __hip_bfloat16* __restrict__ Erb) {
  int i = blockIdx.x * 256 + threadIdx.x;  // 16384 threads x 4 elems
  float4 v = *(const float4*)&Er[(size_t)i * 4];
  __hip_bfloat16 o[4];
  o[0] = __float2bfloat16(v.x); o[1] = __float2bfloat16(v.y);
  o[2] = __float2bfloat16(v.z); o[3] = __float2bfloat16(v.w);
  *(uint2*)&Erb[(size_t)i * 4] = *(const uint2*)o;
}

// ---------------- layernorm (fp32 in -> bf16 out) ----------------
__global__ __launch_bounds__(256) void ln_kernel(const float* __restrict__ X,
                                                 const float* __restrict__ w,
                                                 const float* __restrict__ b,
                                                 __hip_bfloat16* __restrict__ out) {
  int row = blockIdx.x;
  int tid = threadIdx.x;
  const float* xr = X + (size_t)row * DD;
  float4 v = *(const float4*)&xr[tid * 4];
  float s = v.x + v.y + v.z + v.w;
  float s2 = v.x * v.x + v.y * v.y + v.z * v.z + v.w * v.w;
#pragma unroll
  for (int m = 1; m < 64; m <<= 1) {
    s += __shfl_xor(s, m);
    s2 += __shfl_xor(s2, m);
  }
  __shared__ float ps[4], ps2[4];
  int wv_ = tid >> 6, lane = tid & 63;
  if (lane == 0) { ps[wv_] = s; ps2[wv_] = s2; }
  __syncthreads();
  float ts = ps[0] + ps[1] + ps[2] + ps[3];
  float ts2 = ps2[0] + ps2[1] + ps2[2] + ps2[3];
  float mu = ts * (1.0f / DD);
  float var = ts2 * (1.0f / DD) - mu * mu;
  float rs = rsqrtf(var + 1e-5f);
  float4 wv = *(const float4*)&w[tid * 4];
  float4 bv = *(const float4*)&b[tid * 4];
  __hip_bfloat16 o[4];
  o[0] = __float2bfloat16((v.x - mu) * rs * wv.x + bv.x);
  o[1] = __float2bfloat16((v.y - mu) * rs * wv.y + bv.y);
  o[2] = __float2bfloat16((v.z - mu) * rs * wv.z + bv.z);
  o[3] = __float2bfloat16((v.w - mu) * rs * wv.w + bv.w);
  *(uint2*)&out[(size_t)row * DD + tid * 4] = *(const uint2*)o;
}

// ---------------- bf16 MFMA GEMM, 128x128 tile, depth-2 counted-vmcnt pipeline ----------------
// C = A(MxK) * Bt(NxK)^T + bias;  EPI: 0 = bf16 out, 1 = GELU->bf16, 2 = fp32 + resid
template <int EPI>
__global__ __launch_bounds__(256) void gemm128(const __hip_bfloat16* __restrict__ A,
                                               const __hip_bfloat16* __restrict__ Bt,
                                               const float* __restrict__ bias,
                                               const float* __restrict__ resid,
                                               void* __restrict__ Cout,
                                               int M, int N, int K) {
  __shared__ __hip_bfloat16 a_lds[2][128][32];  // 2 x 8 KB
  __shared__ __hip_bfloat16 b_lds[2][128][32];
  int tid = threadIdx.x, lane = tid & 63, w = tid >> 6;

  // XCD-aware bijective swizzle (grids here are all % 8 == 0)
  int nbx = gridDim.x, nwg = nbx * gridDim.y;
  int orig = blockIdx.y * nbx + blockIdx.x;
  int cpx = nwg >> 3;
  int wgid = (orig & 7) * cpx + (orig >> 3);
  int bm0 = (wgid / nbx) * 128, bn0 = (wgid % nbx) * 128;

  int wr = w >> 1, wc = w & 1;
  const int fr = lane & 15, fk = (lane >> 4) * 8;

  // staging: wave w covers rows 32w..32w+31; lane l -> row l/4, kcol (l%4)*8
  const __hip_bfloat16* aptr = A + (size_t)(bm0 + 32 * w + (lane >> 2)) * K + (lane & 3) * 8;
  const __hip_bfloat16* bptr = Bt + (size_t)(bn0 + 32 * w + (lane >> 2)) * K + (lane & 3) * 8;

#define STAGE(bi)                                        \
  do {                                                   \
    GLOAD16(aptr, &a_lds[bi][32 * w][0]);                \
    GLOAD16(aptr + (size_t)16 * K, &a_lds[bi][32 * w + 16][0]); \
    GLOAD16(bptr, &b_lds[bi][32 * w][0]);                \
    GLOAD16(bptr + (size_t)16 * K, &b_lds[bi][32 * w + 16][0]); \
    aptr += 32; bptr += 32;                              \
  } while (0)

  f32x4 acc[4][4] = {};

  // prologue: stage tiles 0 and 1 (8 loads in flight)
  STAGE(0);
  STAGE(1);

  int nsteps = K >> 5;
  for (int t = 0; t < nsteps; ++t) {
    // wait only for tile t's 4 loads; tile t+1's stay in flight across the barrier
    if (t < nsteps - 1) {
      asm volatile("s_waitcnt vmcnt(4)" ::: "memory");
    } else {
      asm volatile("s_waitcnt vmcnt(0)" ::: "memory");
    }
    __builtin_amdgcn_s_barrier();
    asm volatile("" ::: "memory");

    int cur = t & 1;
    bf16x8 af[4], bfv[4];
#pragma unroll
    for (int m = 0; m < 4; ++m)
      af[m] = *(const bf16x8*)&a_lds[cur][64 * wr + 16 * m + fr][fk];
#pragma unroll
    for (int n = 0; n < 4; ++n)
      bfv[n] = *(const bf16x8*)&b_lds[cur][64 * wc + 16 * n + fr][fk];
#pragma unroll
    for (int m = 0; m < 4; ++m)
#pragma unroll
      for (int n = 0; n < 4; ++n)
        acc[m][n] = __builtin_amdgcn_mfma_f32_16x16x32_bf16(af[m], bfv[n], acc[m][n], 0, 0, 0);

    asm volatile("" ::: "memory");
    __builtin_amdgcn_s_barrier();  // all waves done reading buf[cur]
    if (t + 2 < nsteps) STAGE(cur);  // overwrite freed buffer with tile t+2
  }
#undef STAGE

  // epilogue
#pragma unroll
  for (int n = 0; n < 4; ++n) {
    int col = bn0 + 64 * wc + 16 * n + fr;
    float bsv = bias[col];
#pragma unroll
    for (int m = 0; m < 4; ++m) {
      int rowb = bm0 + 64 * wr + 16 * m + (lane >> 4) * 4;
#pragma unroll
      for (int j = 0; j < 4; ++j) {
        int row = rowb + j;
        float v = acc[m][n][j] + bsv;
        if (EPI == 1) v = 0.5f * v * (1.0f + erff(v * 0.7071067811865476f));
        if (EPI == 2) {
          ((float*)Cout)[(size_t)row * N + col] = v + resid[(size_t)row * N + col];
        } else {
          ((__hip_bfloat16*)Cout)[(size_t)row * N + col] = __float2bfloat16(v);
        }
      }
    }
  }
}

// ---------------- MFMA flash attention with relative-position skew ----------------
__global__ __launch_bounds__(256) void attn_mfma(const __hip_bfloat16* __restrict__ qkv,
                                                 const __hip_bfloat16* __restrict__ Erb,
                                                 __hip_bfloat16* __restrict__ Y) {
  __shared__ __hip_bfloat16 q_s[64][72];
  __shared__ __hip_bfloat16 k_s[64][72];
  __shared__ __hip_bfloat16 er_s[128][72];
  __shared__ __hip_bfloat16 p_s[4][16][72];
  __shared__ __hip_bfloat16 g_s[4][16][136];
  __shared__ __hip_bfloat16 vt_s[64 * 64];  // transposed V, XOR-swizzled

  int bid = blockIdx.x;
  int qi = 15 - (bid >> 6);
  int head = bid & 63;
  int h = head & 15, b = head >> 4;
  int l0 = qi * 64;
  int tid = threadIdx.x, lane = tid & 63, w = tid >> 6;

  const __hip_bfloat16* base = qkv + (size_t)b * (LL * 3072) + h * 64;

  {
    int r = tid >> 2, d0 = (tid & 3) * 16;
    const __hip_bfloat16* src = base + (size_t)(l0 + r) * 3072 + d0;
    *(uint4*)&q_s[r][d0] = *(const uint4*)src;
    *(uint4*)&q_s[r][d0 + 8] = *(const uint4*)(src + 8);
  }
  __syncthreads();
  bf16x8 qf[2];
  {
    int r = 16 * w + (lane & 15), kc = (lane >> 4) * 8;
    qf[0] = *(const bf16x8*)&q_s[r][kc];
    qf[1] = *(const bf16x8*)&q_s[r][kc + 32];
  }

  f32x4 oacc[4] = {};
  float m_run[4], s_run[4];
#pragma unroll
  for (int j = 0; j < 4; ++j) { m_run[j] = -1e30f; s_run[j] = 0.f; }

  for (int t = 0; t <= qi; ++t) {
    int c0 = t * 64;
    __syncthreads();
    {
      int r = tid >> 2, d0 = (tid & 3) * 16;
      const __hip_bfloat16* src = base + 1024 + (size_t)(c0 + r) * 3072 + d0;
      *(uint4*)&k_s[r][d0] = *(const uint4*)src;
      *(uint4*)&k_s[r][d0 + 8] = *(const uint4*)(src + 8);
    }
    {
      int c = (tid >> 3) * 2, d0 = (tid & 7) * 8;
      const __hip_bfloat16* s0 = base + 2048 + (size_t)(c0 + c) * 3072 + d0;
      uint4 u0 = *(const uint4*)s0;
      uint4 u1 = *(const uint4*)(s0 + 3072);
      const uint16_t* h0 = (const uint16_t*)&u0;
      const uint16_t* h1 = (const uint16_t*)&u1;
#pragma unroll
      for (int j = 0; j < 8; ++j) {
        int d = d0 + j;
        uint32_t pk = (uint32_t)h0[j] | ((uint32_t)h1[j] << 16);
        uint32_t byte = ((uint32_t)d << 7) + 2u * (uint32_t)c;
        byte ^= (uint32_t)(((d & 7) ^ (d >> 3)) << 4);
        *(uint32_t*)((char*)vt_s + byte) = pk;
      }
    }
    {  // stage Er band (pre-converted bf16): pure vector copies
      int jj = tid >> 1, ch = (tid & 1) * 32;
      int m = 960 + c0 - l0 + jj;
      m = min(max(m, 0), 1023);
      const __hip_bfloat16* src = Erb + (size_t)m * 64 + ch;
      *(uint4*)&er_s[jj][ch]      = *(const uint4*)src;
      *(uint4*)&er_s[jj][ch + 8]  = *(const uint4*)(src + 8);
      *(uint4*)&er_s[jj][ch + 16] = *(const uint4*)(src + 16);
      *(uint4*)&er_s[jj][ch + 24] = *(const uint4*)(src + 24);
    }
    __syncthreads();

    f32x4 sacc[4] = {};
#pragma unroll
    for (int f = 0; f < 4; ++f) {
      int cc = 16 * f + (lane & 15), kc = (lane >> 4) * 8;
      bf16x8 k0 = *(const bf16x8*)&k_s[cc][kc];
      bf16x8 k1 = *(const bf16x8*)&k_s[cc][kc + 32];
      sacc[f] = __builtin_amdgcn_mfma_f32_16x16x32_bf16(qf[0], k0, sacc[f], 0, 0, 0);
      sacc[f] = __builtin_amdgcn_mfma_f32_16x16x32_bf16(qf[1], k1, sacc[f], 0, 0, 0);
    }
#pragma unroll
    for (int g = 0; g < 8; ++g) {
      int cc = 16 * g + (lane & 15), kc = (lane >> 4) * 8;
      bf16x8 e0 = *(const bf16x8*)&er_s[cc][kc];
      bf16x8 e1 = *(const bf16x8*)&er_s[cc][kc + 32];
      f32x4 gacc = {};
      gacc = __builtin_amdgcn_mfma_f32_16x16x32_bf16(qf[0], e0, gacc, 0, 0, 0);
      gacc = __builtin_amdgcn_mfma_f32_16x16x32_bf16(qf[1], e1, gacc, 0, 0, 0);
#pragma unroll
      for (int j = 0; j < 4; ++j) {
        int r = (lane >> 4) * 4 + j;
        g_s[w][r][16 * g + (lane & 15)] = __float2bfloat16(gacc[j]);
      }
    }

    float sv[4][4];
#pragma unroll
    for (int f = 0; f < 4; ++f) {
#pragma unroll
      for (int j = 0; j < 4; ++j) {
        int r = (lane >> 4) * 4 + j;
        int c = 16 * f + (lane & 15);
        int jj = c - (16 * w + r) + 63;
        float g = __bfloat162float(g_s[w][r][jj]);
        float val = (sacc[f][j] + g) * 0.125f;
        if (t == qi && c > 16 * w + r) val = -1e30f;
        sv[f][j] = val;
      }
    }
    float alpha[4];
#pragma unroll
    for (int j = 0; j < 4; ++j) {
      float tm = fmaxf(fmaxf(sv[0][j], sv[1][j]), fmaxf(sv[2][j], sv[3][j]));
      tm = fmaxf(tm, __shfl_xor(tm, 1));
      tm = fmaxf(tm, __shfl_xor(tm, 2));
      tm = fmaxf(tm, __shfl_xor(tm, 4));
      tm = fmaxf(tm, __shfl_xor(tm, 8));
      float nm = fmaxf(m_run[j], tm);
      alpha[j] = __expf(m_run[j] - nm);
      m_run[j] = nm;
    }
#pragma unroll
    for (int f = 0; f < 4; ++f)
#pragma unroll
      for (int j = 0; j < 4; ++j)
        sv[f][j] = __expf(sv[f][j] - m_run[j]);
#pragma unroll
    for (int j = 0; j < 4; ++j) {
      float ps = sv[0][j] + sv[1][j] + sv[2][j] + sv[3][j];
      ps += __shfl_xor(ps, 1); ps += __shfl_xor(ps, 2);
      ps += __shfl_xor(ps, 4); ps += __shfl_xor(ps, 8);
      s_run[j] = s_run[j] * alpha[j] + ps;
    }
#pragma unroll
    for (int f = 0; f < 4; ++f)
#pragma unroll
      for (int j = 0; j < 4; ++j)
        oacc[f][j] *= alpha[j];
#pragma unroll
    for (int f = 0; f < 4; ++f)
#pragma unroll
      for (int j = 0; j < 4; ++j) {
        int r = (lane >> 4) * 4 + j;
        p_s[w][r][16 * f + (lane & 15)] = __float2bfloat16(sv[f][j]);
      }
#pragma unroll
    for (int kk = 0; kk < 2; ++kk) {
      bf16x8 pf = *(const bf16x8*)&p_s[w][lane & 15][(lane >> 4) * 8 + 32 * kk];
#pragma unroll
      for (int f = 0; f < 4; ++f) {
        int d = 16 * f + (lane & 15);
        int cc = (lane >> 4) * 8 + 32 * kk;
        uint32_t byte = ((uint32_t)d << 7) + 2u * (uint32_t)cc;
        byte ^= (uint32_t)(((d & 7) ^ (d >> 3)) << 4);
        bf16x8 vf = *(const bf16x8*)((char*)vt_s + byte);
        oacc[f] = __builtin_amdgcn_mfma_f32_16x16x32_bf16(pf, vf, oacc[f], 0, 0, 0);
      }
    }
  }

#pragma unroll
  for (int f = 0; f < 4; ++f)
#pragma unroll
    for (int j = 0; j < 4; ++j) {
      int r = 16 * w + (lane >> 4) * 4 + j;
      int d = 16 * f + (lane & 15);
      float o = oacc[f][j] / s_run[j];
      Y[(size_t)(b * LL + l0 + r) * DD + h * 64 + d] = __float2bfloat16(o);
    }
}

// ---------------- launch ----------------
extern "C" void kernel_launch(void* const* d_in, const int* in_sizes, int n_in,
                              void* d_out, int out_size, void* d_ws, size_t ws_size,
                              hipStream_t stream) {
  (void)in_sizes; (void)n_in; (void)out_size; (void)ws_size;
  const float* x     = (const float*)d_in[0];
  const float* ln1w  = (const float*)d_in[1];
  const float* ln1b  = (const float*)d_in[2];
  const float* Wqkv  = (const float*)d_in[3];
  const float* bqkv  = (const float*)d_in[4];
  const float* Wproj = (const float*)d_in[5];
  const float* bproj = (const float*)d_in[6];
  const float* Er    = (const float*)d_in[7];
  const float* ln2w  = (const float*)d_in[8];
  const float* ln2b  = (const float*)d_in[9];
  const float* Wfc   = (const float*)d_in[10];
  const float* bfc   = (const float*)d_in[11];
  const float* Wfc2  = (const float*)d_in[12];
  const float* bfc2  = (const float*)d_in[13];
  float* out = (float*)d_out;

  char* ws = (char*)d_ws;
  const size_t MB = 1ull << 20;
  __hip_bfloat16* h1    = (__hip_bfloat16*)(ws + 0);        // 8 MB
  __hip_bfloat16* qkvb  = (__hip_bfloat16*)(ws + 8 * MB);   // 24 MB
  __hip_bfloat16* mbuf  = (__hip_bfloat16*)(ws + 0);        // 32 MB (aliases h1+qkvb)
  __hip_bfloat16* yb    = (__hip_bfloat16*)(ws + 32 * MB);  // 8 MB
  __hip_bfloat16* h2    = (__hip_bfloat16*)(ws + 32 * MB);  // 8 MB (aliases yb)
  float*          x2    = (float*)(ws + 40 * MB);           // 16 MB
  __hip_bfloat16* Wqkvt = (__hip_bfloat16*)(ws + 56 * MB);  // 6 MB
  __hip_bfloat16* Erb   = (__hip_bfloat16*)(ws + 62 * MB);  // 128 KB (gap)
  __hip_bfloat16* Wprojt= (__hip_bfloat16*)(ws + 63 * MB);  // 2 MB
  __hip_bfloat16* Wfct  = (__hip_bfloat16*)(ws + 66 * MB);  // 8 MB
  __hip_bfloat16* Wfc2t = (__hip_bfloat16*)(ws + 75 * MB);  // 8 MB

  dim3 blk(256);

  transpose_cvt<<<dim3(3072 / 32, 1024 / 32), blk, 0, stream>>>(Wqkv, Wqkvt, 1024, 3072);
  transpose_cvt<<<dim3(1024 / 32, 1024 / 32), blk, 0, stream>>>(Wproj, Wprojt, 1024, 1024);
  transpose_cvt<<<dim3(4096 / 32, 1024 / 32), blk, 0, stream>>>(Wfc, Wfct, 1024, 4096);
  transpose_cvt<<<dim3(1024 / 32, 4096 / 32), blk, 0, stream>>>(Wfc2, Wfc2t, 4096, 1024);
  cvt_er<<<dim3(64), blk, 0, stream>>>(Er, Erb);

  ln_kernel<<<4096, blk, 0, stream>>>(x, ln1w, ln1b, h1);

  gemm128<0><<<dim3(3072 / 128, 4096 / 128), blk, 0, stream>>>(
      h1, Wqkvt, bqkv, nullptr, qkvb, 4096, 3072, 1024);

  attn_mfma<<<dim3(1024), blk, 0, stream>>>(qkvb, Erb, yb);

  gemm128<2><<<dim3(1024 / 128, 4096 / 128), blk, 0, stream>>>(
      yb, Wprojt, bproj, x, x2, 4096, 1024, 1024);

  ln_kernel<<<4096, blk, 0, stream>>>(x2, ln2w, ln2b, h2);

  gemm128<1><<<dim3(4096 / 128, 4096 / 128), blk, 0, stream>>>(
      h2, Wfct, bfc, nullptr, mbuf, 4096, 4096, 1024);

  gemm128<2><<<dim3(1024 / 128, 4096 / 128), blk, 0, stream>>>(
      mbuf, Wfc2t, bfc2, x2, out, 4096, 1024, 4096);
}

// Round 8
// 274.809 us; speedup vs baseline: 4.5186x; 1.0810x over previous
//
#include <hip/hip_runtime.h>
#include <hip/hip_bf16.h>
#include <math.h>

typedef __attribute__((ext_vector_type(8))) __bf16 bf16x8;
typedef __attribute__((ext_vector_type(4))) float f32x4;

#define LL 1024
#define DD 1024
#define HH 16

#define GLOAD16(g, l)                                              \
  __builtin_amdgcn_global_load_lds(                                \
      (const __attribute__((address_space(1))) void*)(g),          \
      (__attribute__((address_space(3))) void*)(l), 16, 0, 0)

#define FENCE asm volatile("" ::: "memory")
#define BARRIER do { FENCE; __builtin_amdgcn_s_barrier(); FENCE; } while (0)
#define SCHEDB __builtin_amdgcn_sched_barrier(0)

// ---------------- weight transpose + fp32->bf16 ----------------
__global__ __launch_bounds__(256) void transpose_cvt(const float* __restrict__ W,
                                                     __hip_bfloat16* __restrict__ Wt,
                                                     int R, int C) {
  __shared__ float tile[32][33];
  int tx = threadIdx.x;
  int r0 = blockIdx.y * 32, c0 = blockIdx.x * 32;
  int r = tx >> 3, c4 = (tx & 7) * 4;
  float4 v = *(const float4*)&W[(size_t)(r0 + r) * C + c0 + c4];
  tile[r][c4 + 0] = v.x; tile[r][c4 + 1] = v.y;
  tile[r][c4 + 2] = v.z; tile[r][c4 + 3] = v.w;
  __syncthreads();
  int c = tx >> 3, r4 = (tx & 7) * 4;
  __hip_bfloat16 o[4];
#pragma unroll
  for (int j = 0; j < 4; ++j) o[j] = __float2bfloat16(tile[r4 + j][c]);
  *(uint2*)&Wt[(size_t)(c0 + c) * R + r0 + r4] = *(const uint2*)o;
}

// ---------------- Er fp32 -> bf16 (once) ----------------
__global__ __launch_bounds__(256) void cvt_er(const float* __restrict__ Er,
                                              __hip_bfloat16* __restrict__ Erb) {
  int i = blockIdx.x * 256 + threadIdx.x;
  float4 v = *(const float4*)&Er[(size_t)i * 4];
  __hip_bfloat16 o[4];
  o[0] = __float2bfloat16(v.x); o[1] = __float2bfloat16(v.y);
  o[2] = __float2bfloat16(v.z); o[3] = __float2bfloat16(v.w);
  *(uint2*)&Erb[(size_t)i * 4] = *(const uint2*)o;
}

// ---------------- layernorm (fp32 in -> bf16 out) ----------------
__global__ __launch_bounds__(256) void ln_kernel(const float* __restrict__ X,
                                                 const float* __restrict__ w,
                                                 const float* __restrict__ b,
                                                 __hip_bfloat16* __restrict__ out) {
  int row = blockIdx.x;
  int tid = threadIdx.x;
  const float* xr = X + (size_t)row * DD;
  float4 v = *(const float4*)&xr[tid * 4];
  float s = v.x + v.y + v.z + v.w;
  float s2 = v.x * v.x + v.y * v.y + v.z * v.z + v.w * v.w;
#pragma unroll
  for (int m = 1; m < 64; m <<= 1) {
    s += __shfl_xor(s, m);
    s2 += __shfl_xor(s2, m);
  }
  __shared__ float ps[4], ps2[4];
  int wv_ = tid >> 6, lane = tid & 63;
  if (lane == 0) { ps[wv_] = s; ps2[wv_] = s2; }
  __syncthreads();
  float ts = ps[0] + ps[1] + ps[2] + ps[3];
  float ts2 = ps2[0] + ps2[1] + ps2[2] + ps2[3];
  float mu = ts * (1.0f / DD);
  float var = ts2 * (1.0f / DD) - mu * mu;
  float rs = rsqrtf(var + 1e-5f);
  float4 wv = *(const float4*)&w[tid * 4];
  float4 bv = *(const float4*)&b[tid * 4];
  __hip_bfloat16 o[4];
  o[0] = __float2bfloat16((v.x - mu) * rs * wv.x + bv.x);
  o[1] = __float2bfloat16((v.y - mu) * rs * wv.y + bv.y);
  o[2] = __float2bfloat16((v.z - mu) * rs * wv.z + bv.z);
  o[3] = __float2bfloat16((v.w - mu) * rs * wv.w + bv.w);
  *(uint2*)&out[(size_t)row * DD + tid * 4] = *(const uint2*)o;
}

// ===================== 256x256 8-phase GEMM (T1+T2+T3+T4+T5) =====================
// C = A(MxK) * Bt(NxK)^T + bias. 8 waves (2M x 4N), BK=64, LDS 128KB.
// Swizzle: LDS byte (row*128 + col2) ^ ((row&7)<<4); linear gload_lds dest +
// inverse-swizzled global source + swizzled ds_read (both-sides rule).
// vmcnt(4) at phases 4/8: steady state keeps exactly the 2 newest half-tiles
// (4 loads) in flight; last iteration drains with vmcnt(0).
template <int EPI>
__global__ __launch_bounds__(512) void gemm256(const __hip_bfloat16* __restrict__ A,
                                               const __hip_bfloat16* __restrict__ Bt,
                                               const float* __restrict__ bias,
                                               const float* __restrict__ resid,
                                               void* __restrict__ Cout,
                                               int M, int N, int K) {
  __shared__ __hip_bfloat16 Ab[2][2][128][64];  // [dbuf][half][row][col] 64KB
  __shared__ __hip_bfloat16 Bb[2][2][128][64];  // 64KB
  const int tid = threadIdx.x, lane = tid & 63, w = tid >> 6;
  const int wm = w >> 2, wn = w & 3;

  int nbx = gridDim.x, nwg = nbx * gridDim.y;
  int orig = blockIdx.y * nbx + blockIdx.x;
  int cpx = nwg >> 3;
  int wgid = (orig & 7) * cpx + (orig >> 3);   // grids are %8==0
  int bm0 = (wgid / nbx) * 256, bn0 = (wgid % nbx) * 256;

  const int srow = lane >> 3;                  // 0..7
  const int scol = ((lane & 7) ^ srow) * 8;    // inverse-swizzled source col (elems)
  const int fr = lane & 15, kq = lane >> 4;

  auto stageA = [&](int d, int half, int k0) {
    const __hip_bfloat16* g0 =
        A + (size_t)(bm0 + half * 128 + w * 16 + srow) * K + k0 + scol;
    char* dst = (char*)&Ab[d][half][0][0] + w * 2048;
    GLOAD16(g0, dst);
    GLOAD16(g0 + (size_t)8 * K, dst + 1024);
  };
  auto stageB = [&](int d, int half, int k0) {
    const __hip_bfloat16* g0 =
        Bt + (size_t)(bn0 + half * 128 + w * 16 + srow) * K + k0 + scol;
    char* dst = (char*)&Bb[d][half][0][0] + w * 2048;
    GLOAD16(g0, dst);
    GLOAD16(g0 + (size_t)8 * K, dst + 1024);
  };
  auto ldA = [&](int d, int r, int ks) -> bf16x8 {
    int byte = r * 128 + (((ks * 32 + kq * 8) * 2) ^ ((r & 7) << 4));
    return *(const bf16x8*)((const char*)&Ab[d][wm][0][0] + byte);
  };
  auto ldB = [&](int d, int r, int ks) -> bf16x8 {
    int byte = r * 128 + (((ks * 32 + kq * 8) * 2) ^ ((r & 7) << 4));
    return *(const bf16x8*)((const char*)&Bb[d][wn >> 1][0][0] + byte);
  };

  f32x4 acc[8][4] = {};
  bf16x8 a0[8], a1[8], b0[4], b1[4];

  auto rdA = [&](bf16x8* dst, int d, int mfb) {
#pragma unroll
    for (int mf = 0; mf < 4; ++mf)
#pragma unroll
      for (int ks = 0; ks < 2; ++ks)
        dst[mf * 2 + ks] = ldA(d, (mfb + mf) * 16 + fr, ks);
  };
  auto rdB = [&](bf16x8* dst, int d, int nfb) {
#pragma unroll
    for (int nf = 0; nf < 2; ++nf)
#pragma unroll
      for (int ks = 0; ks < 2; ++ks)
        dst[nf * 2 + ks] = ldB(d, (wn & 1) * 64 + (nfb + nf) * 16 + fr, ks);
  };
  auto mmq = [&](int mo, int no, bf16x8* ar, bf16x8* br) {
    __builtin_amdgcn_s_setprio(1);
#pragma unroll
    for (int mf = 0; mf < 4; ++mf)
#pragma unroll
      for (int nf = 0; nf < 2; ++nf)
#pragma unroll
        for (int ks = 0; ks < 2; ++ks)
          acc[mo + mf][no + nf] = __builtin_amdgcn_mfma_f32_16x16x32_bf16(
              ar[mf * 2 + ks], br[nf * 2 + ks], acc[mo + mf][no + nf], 0, 0, 0);
    __builtin_amdgcn_s_setprio(0);
  };

  // prologue: A(0),B(0) buf0 + A(1) buf1 -> 12 loads; keep A(1) (4) in flight
  stageA(0, 0, 0); stageA(0, 1, 0);
  stageB(0, 0, 0); stageB(0, 1, 0);
  stageA(1, 0, 64); stageA(1, 1, 64);
  asm volatile("s_waitcnt vmcnt(4)" ::: "memory");
  BARRIER;

  const int niter = (K >> 6) >> 1;  // K-tiles processed 2 per iteration
  for (int i = 0; i < niter; ++i) {
    const bool last = (i == niter - 1);
    const int k1 = (2 * i + 1) * 64, k2 = (2 * i + 2) * 64, k3 = (2 * i + 3) * 64;
    // ph1: buf0 reads mf0-3/nf0-1; stage B-lo(kt+1)->buf1
    rdA(a0, 0, 0); rdB(b0, 0, 0);
    stageB(1, 0, k1);
    BARRIER; SCHEDB; mmq(0, 0, a0, b0); SCHEDB; BARRIER;
    // ph2
    rdA(a1, 0, 4);
    stageB(1, 1, k1);
    BARRIER; SCHEDB; mmq(4, 0, a1, b0); SCHEDB; BARRIER;
    // ph3
    rdB(b1, 0, 2);
    if (!last) stageA(0, 0, k2);
    BARRIER; SCHEDB; mmq(0, 2, a0, b1); SCHEDB; BARRIER;
    // ph4  (buffer switch: ensure kt+1 fully landed)
    if (!last) stageA(0, 1, k2);
    BARRIER; SCHEDB; mmq(4, 2, a1, b1); SCHEDB;
    if (last) { asm volatile("s_waitcnt vmcnt(0)" ::: "memory"); }
    else      { asm volatile("s_waitcnt vmcnt(4)" ::: "memory"); }
    BARRIER;
    // ph5: buf1
    rdA(a0, 1, 0); rdB(b0, 1, 0);
    if (!last) stageB(0, 0, k2);
    BARRIER; SCHEDB; mmq(0, 0, a0, b0); SCHEDB; BARRIER;
    // ph6
    rdA(a1, 1, 4);
    if (!last) stageB(0, 1, k2);
    BARRIER; SCHEDB; mmq(4, 0, a1, b0); SCHEDB; BARRIER;
    // ph7
    rdB(b1, 1, 2);
    if (!last) stageA(1, 0, k3);
    BARRIER; SCHEDB; mmq(0, 2, a0, b1); SCHEDB; BARRIER;
    // ph8
    if (!last) stageA(1, 1, k3);
    BARRIER; SCHEDB; mmq(4, 2, a1, b1); SCHEDB;
    if (last) { asm volatile("s_waitcnt vmcnt(0)" ::: "memory"); }
    else      { asm volatile("s_waitcnt vmcnt(4)" ::: "memory"); }
    BARRIER;
  }

  // epilogue
#pragma unroll
  for (int nf = 0; nf < 4; ++nf) {
    int col = bn0 + wn * 64 + nf * 16 + fr;
    float bsv = bias[col];
#pragma unroll
    for (int mf = 0; mf < 8; ++mf) {
      int rowb = bm0 + wm * 128 + mf * 16 + (lane >> 4) * 4;
#pragma unroll
      for (int j = 0; j < 4; ++j) {
        int row = rowb + j;
        float v = acc[mf][nf][j] + bsv;
        if (EPI == 1) v = 0.5f * v * (1.0f + erff(v * 0.7071067811865476f));
        if (EPI == 2) {
          ((float*)Cout)[(size_t)row * N + col] = v + resid[(size_t)row * N + col];
        } else {
          ((__hip_bfloat16*)Cout)[(size_t)row * N + col] = __float2bfloat16(v);
        }
      }
    }
  }
}

// ===================== 128x128 4-phase GEMM (narrow-N variant) =====================
// 4 waves (2M x 2N), BK=64, LDS 64KB. Same swizzle + counted-vmcnt derivation.
template <int EPI>
__global__ __launch_bounds__(256) void gemm128p(const __hip_bfloat16* __restrict__ A,
                                                const __hip_bfloat16* __restrict__ Bt,
                                                const float* __restrict__ bias,
                                                const float* __restrict__ resid,
                                                void* __restrict__ Cout,
                                                int M, int N, int K) {
  __shared__ __hip_bfloat16 Ab[2][2][64][64];
  __shared__ __hip_bfloat16 Bb[2][2][64][64];
  const int tid = threadIdx.x, lane = tid & 63, w = tid >> 6;
  const int wm = w >> 1, wn = w & 1;

  int nbx = gridDim.x, nwg = nbx * gridDim.y;
  int orig = blockIdx.y * nbx + blockIdx.x;
  int cpx = nwg >> 3;
  int wgid = (orig & 7) * cpx + (orig >> 3);
  int bm0 = (wgid / nbx) * 128, bn0 = (wgid % nbx) * 128;

  const int srow = lane >> 3;
  const int scol = ((lane & 7) ^ srow) * 8;
  const int fr = lane & 15, kq = lane >> 4;

  auto stageA = [&](int d, int half, int k0) {
    const __hip_bfloat16* g0 =
        A + (size_t)(bm0 + half * 64 + w * 16 + srow) * K + k0 + scol;
    char* dst = (char*)&Ab[d][half][0][0] + w * 2048;
    GLOAD16(g0, dst);
    GLOAD16(g0 + (size_t)8 * K, dst + 1024);
  };
  auto stageB = [&](int d, int half, int k0) {
    const __hip_bfloat16* g0 =
        Bt + (size_t)(bn0 + half * 64 + w * 16 + srow) * K + k0 + scol;
    char* dst = (char*)&Bb[d][half][0][0] + w * 2048;
    GLOAD16(g0, dst);
    GLOAD16(g0 + (size_t)8 * K, dst + 1024);
  };
  auto ldA = [&](int d, int r, int ks) -> bf16x8 {
    int byte = r * 128 + (((ks * 32 + kq * 8) * 2) ^ ((r & 7) << 4));
    return *(const bf16x8*)((const char*)&Ab[d][wm][0][0] + byte);
  };
  auto ldB = [&](int d, int r, int ks) -> bf16x8 {
    int byte = r * 128 + (((ks * 32 + kq * 8) * 2) ^ ((r & 7) << 4));
    return *(const bf16x8*)((const char*)&Bb[d][wn][0][0] + byte);
  };

  f32x4 acc[4][4] = {};
  bf16x8 aA[8], b0[4], b1[4];

  auto rdA = [&](int d) {
#pragma unroll
    for (int mf = 0; mf < 4; ++mf)
#pragma unroll
      for (int ks = 0; ks < 2; ++ks)
        aA[mf * 2 + ks] = ldA(d, mf * 16 + fr, ks);
  };
  auto rdB = [&](bf16x8* dst, int d, int nfb) {
#pragma unroll
    for (int nf = 0; nf < 2; ++nf)
#pragma unroll
      for (int ks = 0; ks < 2; ++ks)
        dst[nf * 2 + ks] = ldB(d, (nfb + nf) * 16 + fr, ks);
  };
  auto mmq = [&](int no, bf16x8* br) {
    __builtin_amdgcn_s_setprio(1);
#pragma unroll
    for (int mf = 0; mf < 4; ++mf)
#pragma unroll
      for (int nf = 0; nf < 2; ++nf)
#pragma unroll
        for (int ks = 0; ks < 2; ++ks)
          acc[mf][no + nf] = __builtin_amdgcn_mfma_f32_16x16x32_bf16(
              aA[mf * 2 + ks], br[nf * 2 + ks], acc[mf][no + nf], 0, 0, 0);
    __builtin_amdgcn_s_setprio(0);
  };

  // prologue
  stageA(0, 0, 0); stageA(0, 1, 0);
  stageB(0, 0, 0); stageB(0, 1, 0);
  stageA(1, 0, 64); stageA(1, 1, 64);
  asm volatile("s_waitcnt vmcnt(4)" ::: "memory");
  BARRIER;

  const int niter = (K >> 6) >> 1;
  for (int i = 0; i < niter; ++i) {
    const bool last = (i == niter - 1);
    const int k1 = (2 * i + 1) * 64, k2 = (2 * i + 2) * 64, k3 = (2 * i + 3) * 64;
    // ph1: buf0; stage B(kt+1)->buf1
    rdA(0); rdB(b0, 0, 0);
    stageB(1, 0, k1); stageB(1, 1, k1);
    BARRIER; SCHEDB; mmq(0, b0); SCHEDB; BARRIER;
    // ph2: stage A(kt+2)->buf0; buffer switch wait
    rdB(b1, 0, 2);
    if (!last) { stageA(0, 0, k2); stageA(0, 1, k2); }
    BARRIER; SCHEDB; mmq(2, b1); SCHEDB;
    if (last) { asm volatile("s_waitcnt vmcnt(0)" ::: "memory"); }
    else      { asm volatile("s_waitcnt vmcnt(4)" ::: "memory"); }
    BARRIER;
    // ph3: buf1; stage B(kt+2)->buf0
    rdA(1); rdB(b0, 1, 0);
    if (!last) { stageB(0, 0, k2); stageB(0, 1, k2); }
    BARRIER; SCHEDB; mmq(0, b0); SCHEDB; BARRIER;
    // ph4: stage A(kt+3)->buf1; switch wait
    rdB(b1, 1, 2);
    if (!last) { stageA(1, 0, k3); stageA(1, 1, k3); }
    BARRIER; SCHEDB; mmq(2, b1); SCHEDB;
    if (last) { asm volatile("s_waitcnt vmcnt(0)" ::: "memory"); }
    else      { asm volatile("s_waitcnt vmcnt(4)" ::: "memory"); }
    BARRIER;
  }

  // epilogue
#pragma unroll
  for (int nf = 0; nf < 4; ++nf) {
    int col = bn0 + wn * 64 + nf * 16 + fr;
    float bsv = bias[col];
#pragma unroll
    for (int mf = 0; mf < 4; ++mf) {
      int rowb = bm0 + wm * 64 + mf * 16 + (lane >> 4) * 4;
#pragma unroll
      for (int j = 0; j < 4; ++j) {
        int row = rowb + j;
        float v = acc[mf][nf][j] + bsv;
        if (EPI == 1) v = 0.5f * v * (1.0f + erff(v * 0.7071067811865476f));
        if (EPI == 2) {
          ((float*)Cout)[(size_t)row * N + col] = v + resid[(size_t)row * N + col];
        } else {
          ((__hip_bfloat16*)Cout)[(size_t)row * N + col] = __float2bfloat16(v);
        }
      }
    }
  }
}

// ---------------- MFMA flash attention with relative-position skew ----------------
__global__ __launch_bounds__(256) void attn_mfma(const __hip_bfloat16* __restrict__ qkv,
                                                 const __hip_bfloat16* __restrict__ Erb,
                                                 __hip_bfloat16* __restrict__ Y) {
  __shared__ __hip_bfloat16 q_s[64][72];
  __shared__ __hip_bfloat16 k_s[64][72];
  __shared__ __hip_bfloat16 er_s[128][72];
  __shared__ __hip_bfloat16 p_s[4][16][72];
  __shared__ __hip_bfloat16 g_s[4][16][136];
  __shared__ __hip_bfloat16 vt_s[64 * 64];  // transposed V, XOR-swizzled

  int bid = blockIdx.x;
  int qi = 15 - (bid >> 6);
  int head = bid & 63;
  int h = head & 15, b = head >> 4;
  int l0 = qi * 64;
  int tid = threadIdx.x, lane = tid & 63, w = tid >> 6;

  const __hip_bfloat16* base = qkv + (size_t)b * (LL * 3072) + h * 64;

  {
    int r = tid >> 2, d0 = (tid & 3) * 16;
    const __hip_bfloat16* src = base + (size_t)(l0 + r) * 3072 + d0;
    *(uint4*)&q_s[r][d0] = *(const uint4*)src;
    *(uint4*)&q_s[r][d0 + 8] = *(const uint4*)(src + 8);
  }
  __syncthreads();
  bf16x8 qf[2];
  {
    int r = 16 * w + (lane & 15), kc = (lane >> 4) * 8;
    qf[0] = *(const bf16x8*)&q_s[r][kc];
    qf[1] = *(const bf16x8*)&q_s[r][kc + 32];
  }

  f32x4 oacc[4] = {};
  float m_run[4], s_run[4];
#pragma unroll
  for (int j = 0; j < 4; ++j) { m_run[j] = -1e30f; s_run[j] = 0.f; }

  for (int t = 0; t <= qi; ++t) {
    int c0 = t * 64;
    __syncthreads();
    {
      int r = tid >> 2, d0 = (tid & 3) * 16;
      const __hip_bfloat16* src = base + 1024 + (size_t)(c0 + r) * 3072 + d0;
      *(uint4*)&k_s[r][d0] = *(const uint4*)src;
      *(uint4*)&k_s[r][d0 + 8] = *(const uint4*)(src + 8);
    }
    {
      int c = (tid >> 3) * 2, d0 = (tid & 7) * 8;
      const __hip_bfloat16* s0 = base + 2048 + (size_t)(c0 + c) * 3072 + d0;
      uint4 u0 = *(const uint4*)s0;
      uint4 u1 = *(const uint4*)(s0 + 3072);
      const uint16_t* h0 = (const uint16_t*)&u0;
      const uint16_t* h1 = (const uint16_t*)&u1;
#pragma unroll
      for (int j = 0; j < 8; ++j) {
        int d = d0 + j;
        uint32_t pk = (uint32_t)h0[j] | ((uint32_t)h1[j] << 16);
        uint32_t byte = ((uint32_t)d << 7) + 2u * (uint32_t)c;
        byte ^= (uint32_t)(((d & 7) ^ (d >> 3)) << 4);
        *(uint32_t*)((char*)vt_s + byte) = pk;
      }
    }
    {
      int jj = tid >> 1, ch = (tid & 1) * 32;
      int m = 960 + c0 - l0 + jj;
      m = min(max(m, 0), 1023);
      const __hip_bfloat16* src = Erb + (size_t)m * 64 + ch;
      *(uint4*)&er_s[jj][ch]      = *(const uint4*)src;
      *(uint4*)&er_s[jj][ch + 8]  = *(const uint4*)(src + 8);
      *(uint4*)&er_s[jj][ch + 16] = *(const uint4*)(src + 16);
      *(uint4*)&er_s[jj][ch + 24] = *(const uint4*)(src + 24);
    }
    __syncthreads();

    f32x4 sacc[4] = {};
#pragma unroll
    for (int f = 0; f < 4; ++f) {
      int cc = 16 * f + (lane & 15), kc = (lane >> 4) * 8;
      bf16x8 k0 = *(const bf16x8*)&k_s[cc][kc];
      bf16x8 k1 = *(const bf16x8*)&k_s[cc][kc + 32];
      sacc[f] = __builtin_amdgcn_mfma_f32_16x16x32_bf16(qf[0], k0, sacc[f], 0, 0, 0);
      sacc[f] = __builtin_amdgcn_mfma_f32_16x16x32_bf16(qf[1], k1, sacc[f], 0, 0, 0);
    }
#pragma unroll
    for (int g = 0; g < 8; ++g) {
      int cc = 16 * g + (lane & 15), kc = (lane >> 4) * 8;
      bf16x8 e0 = *(const bf16x8*)&er_s[cc][kc];
      bf16x8 e1 = *(const bf16x8*)&er_s[cc][kc + 32];
      f32x4 gacc = {};
      gacc = __builtin_amdgcn_mfma_f32_16x16x32_bf16(qf[0], e0, gacc, 0, 0, 0);
      gacc = __builtin_amdgcn_mfma_f32_16x16x32_bf16(qf[1], e1, gacc, 0, 0, 0);
#pragma unroll
      for (int j = 0; j < 4; ++j) {
        int r = (lane >> 4) * 4 + j;
        g_s[w][r][16 * g + (lane & 15)] = __float2bfloat16(gacc[j]);
      }
    }

    float sv[4][4];
#pragma unroll
    for (int f = 0; f < 4; ++f) {
#pragma unroll
      for (int j = 0; j < 4; ++j) {
        int r = (lane >> 4) * 4 + j;
        int c = 16 * f + (lane & 15);
        int jj = c - (16 * w + r) + 63;
        float g = __bfloat162float(g_s[w][r][jj]);
        float val = (sacc[f][j] + g) * 0.125f;
        if (t == qi && c > 16 * w + r) val = -1e30f;
        sv[f][j] = val;
      }
    }
    float alpha[4];
#pragma unroll
    for (int j = 0; j < 4; ++j) {
      float tm = fmaxf(fmaxf(sv[0][j], sv[1][j]), fmaxf(sv[2][j], sv[3][j]));
      tm = fmaxf(tm, __shfl_xor(tm, 1));
      tm = fmaxf(tm, __shfl_xor(tm, 2));
      tm = fmaxf(tm, __shfl_xor(tm, 4));
      tm = fmaxf(tm, __shfl_xor(tm, 8));
      float nm = fmaxf(m_run[j], tm);
      alpha[j] = __expf(m_run[j] - nm);
      m_run[j] = nm;
    }
#pragma unroll
    for (int f = 0; f < 4; ++f)
#pragma unroll
      for (int j = 0; j < 4; ++j)
        sv[f][j] = __expf(sv[f][j] - m_run[j]);
#pragma unroll
    for (int j = 0; j < 4; ++j) {
      float ps = sv[0][j] + sv[1][j] + sv[2][j] + sv[3][j];
      ps += __shfl_xor(ps, 1); ps += __shfl_xor(ps, 2);
      ps += __shfl_xor(ps, 4); ps += __shfl_xor(ps, 8);
      s_run[j] = s_run[j] * alpha[j] + ps;
    }
#pragma unroll
    for (int f = 0; f < 4; ++f)
#pragma unroll
      for (int j = 0; j < 4; ++j)
        oacc[f][j] *= alpha[j];
#pragma unroll
    for (int f = 0; f < 4; ++f)
#pragma unroll
      for (int j = 0; j < 4; ++j) {
        int r = (lane >> 4) * 4 + j;
        p_s[w][r][16 * f + (lane & 15)] = __float2bfloat16(sv[f][j]);
      }
#pragma unroll
    for (int kk = 0; kk < 2; ++kk) {
      bf16x8 pf = *(const bf16x8*)&p_s[w][lane & 15][(lane >> 4) * 8 + 32 * kk];
#pragma unroll
      for (int f = 0; f < 4; ++f) {
        int d = 16 * f + (lane & 15);
        int cc = (lane >> 4) * 8 + 32 * kk;
        uint32_t byte = ((uint32_t)d << 7) + 2u * (uint32_t)cc;
        byte ^= (uint32_t)(((d & 7) ^ (d >> 3)) << 4);
        bf16x8 vf = *(const bf16x8*)((char*)vt_s + byte);
        oacc[f] = __builtin_amdgcn_mfma_f32_16x16x32_bf16(pf, vf, oacc[f], 0, 0, 0);
      }
    }
  }

#pragma unroll
  for (int f = 0; f < 4; ++f)
#pragma unroll
    for (int j = 0; j < 4; ++j) {
      int r = 16 * w + (lane >> 4) * 4 + j;
      int d = 16 * f + (lane & 15);
      float o = oacc[f][j] / s_run[j];
      Y[(size_t)(b * LL + l0 + r) * DD + h * 64 + d] = __float2bfloat16(o);
    }
}

// ---------------- launch ----------------
extern "C" void kernel_launch(void* const* d_in, const int* in_sizes, int n_in,
                              void* d_out, int out_size, void* d_ws, size_t ws_size,
                              hipStream_t stream) {
  (void)in_sizes; (void)n_in; (void)out_size; (void)ws_size;
  const float* x     = (const float*)d_in[0];
  const float* ln1w  = (const float*)d_in[1];
  const float* ln1b  = (const float*)d_in[2];
  const float* Wqkv  = (const float*)d_in[3];
  const float* bqkv  = (const float*)d_in[4];
  const float* Wproj = (const float*)d_in[5];
  const float* bproj = (const float*)d_in[6];
  const float* Er    = (const float*)d_in[7];
  const float* ln2w  = (const float*)d_in[8];
  const float* ln2b  = (const float*)d_in[9];
  const float* Wfc   = (const float*)d_in[10];
  const float* bfc   = (const float*)d_in[11];
  const float* Wfc2  = (const float*)d_in[12];
  const float* bfc2  = (const float*)d_in[13];
  float* out = (float*)d_out;

  char* ws = (char*)d_ws;
  const size_t MB = 1ull << 20;
  __hip_bfloat16* h1    = (__hip_bfloat16*)(ws + 0);        // 8 MB
  __hip_bfloat16* qkvb  = (__hip_bfloat16*)(ws + 8 * MB);   // 24 MB
  __hip_bfloat16* mbuf  = (__hip_bfloat16*)(ws + 0);        // 32 MB (aliases h1+qkvb)
  __hip_bfloat16* yb    = (__hip_bfloat16*)(ws + 32 * MB);  // 8 MB
  __hip_bfloat16* h2    = (__hip_bfloat16*)(ws + 32 * MB);  // 8 MB (aliases yb)
  float*          x2    = (float*)(ws + 40 * MB);           // 16 MB
  __hip_bfloat16* Wqkvt = (__hip_bfloat16*)(ws + 56 * MB);  // 6 MB
  __hip_bfloat16* Erb   = (__hip_bfloat16*)(ws + 62 * MB);  // 128 KB
  __hip_bfloat16* Wprojt= (__hip_bfloat16*)(ws + 63 * MB);  // 2 MB
  __hip_bfloat16* Wfct  = (__hip_bfloat16*)(ws + 66 * MB);  // 8 MB
  __hip_bfloat16* Wfc2t = (__hip_bfloat16*)(ws + 75 * MB);  // 8 MB

  dim3 blk(256);

  transpose_cvt<<<dim3(3072 / 32, 1024 / 32), blk, 0, stream>>>(Wqkv, Wqkvt, 1024, 3072);
  transpose_cvt<<<dim3(1024 / 32, 1024 / 32), blk, 0, stream>>>(Wproj, Wprojt, 1024, 1024);
  transpose_cvt<<<dim3(4096 / 32, 1024 / 32), blk, 0, stream>>>(Wfc, Wfct, 1024, 4096);
  transpose_cvt<<<dim3(1024 / 32, 4096 / 32), blk, 0, stream>>>(Wfc2, Wfc2t, 4096, 1024);
  cvt_er<<<dim3(64), blk, 0, stream>>>(Er, Erb);

  ln_kernel<<<4096, blk, 0, stream>>>(x, ln1w, ln1b, h1);

  gemm256<0><<<dim3(3072 / 256, 4096 / 256), dim3(512), 0, stream>>>(
      h1, Wqkvt, bqkv, nullptr, qkvb, 4096, 3072, 1024);

  attn_mfma<<<dim3(1024), blk, 0, stream>>>(qkvb, Erb, yb);

  gemm128p<2><<<dim3(1024 / 128, 4096 / 128), blk, 0, stream>>>(
      yb, Wprojt, bproj, x, x2, 4096, 1024, 1024);

  ln_kernel<<<4096, blk, 0, stream>>>(x2, ln2w, ln2b, h2);

  gemm256<1><<<dim3(4096 / 256, 4096 / 256), dim3(512), 0, stream>>>(
      h2, Wfct, bfc, nullptr, mbuf, 4096, 4096, 1024);

  gemm128p<2><<<dim3(1024 / 128, 4096 / 128), blk, 0, stream>>>(
      mbuf, Wfc2t, bfc2, x2, out, 4096, 1024, 4096);
}

// Round 9
// 261.858 us; speedup vs baseline: 4.7421x; 1.0495x over previous
//
#include <hip/hip_runtime.h>
#include <hip/hip_bf16.h>
#include <math.h>

typedef __attribute__((ext_vector_type(8))) __bf16 bf16x8;
typedef __attribute__((ext_vector_type(4))) float f32x4;

#define LL 1024
#define DD 1024
#define HH 16

#define GLOAD16(g, l)                                              \
  __builtin_amdgcn_global_load_lds(                                \
      (const __attribute__((address_space(1))) void*)(g),          \
      (__attribute__((address_space(3))) void*)(l), 16, 0, 0)

#define FENCE asm volatile("" ::: "memory")
#define BARRIER do { FENCE; __builtin_amdgcn_s_barrier(); FENCE; } while (0)
#define SCHEDB __builtin_amdgcn_sched_barrier(0)

// ---------------- weight transpose + fp32->bf16 ----------------
__global__ __launch_bounds__(256) void transpose_cvt(const float* __restrict__ W,
                                                     __hip_bfloat16* __restrict__ Wt,
                                                     int R, int C) {
  __shared__ float tile[32][33];
  int tx = threadIdx.x;
  int r0 = blockIdx.y * 32, c0 = blockIdx.x * 32;
  int r = tx >> 3, c4 = (tx & 7) * 4;
  float4 v = *(const float4*)&W[(size_t)(r0 + r) * C + c0 + c4];
  tile[r][c4 + 0] = v.x; tile[r][c4 + 1] = v.y;
  tile[r][c4 + 2] = v.z; tile[r][c4 + 3] = v.w;
  __syncthreads();
  int c = tx >> 3, r4 = (tx & 7) * 4;
  __hip_bfloat16 o[4];
#pragma unroll
  for (int j = 0; j < 4; ++j) o[j] = __float2bfloat16(tile[r4 + j][c]);
  *(uint2*)&Wt[(size_t)(c0 + c) * R + r0 + r4] = *(const uint2*)o;
}

// ---------------- Er fp32 -> bf16 (once) ----------------
__global__ __launch_bounds__(256) void cvt_er(const float* __restrict__ Er,
                                              __hip_bfloat16* __restrict__ Erb) {
  int i = blockIdx.x * 256 + threadIdx.x;
  float4 v = *(const float4*)&Er[(size_t)i * 4];
  __hip_bfloat16 o[4];
  o[0] = __float2bfloat16(v.x); o[1] = __float2bfloat16(v.y);
  o[2] = __float2bfloat16(v.z); o[3] = __float2bfloat16(v.w);
  *(uint2*)&Erb[(size_t)i * 4] = *(const uint2*)o;
}

// ---------------- layernorm (fp32 in -> bf16 out) ----------------
__global__ __launch_bounds__(256) void ln_kernel(const float* __restrict__ X,
                                                 const float* __restrict__ w,
                                                 const float* __restrict__ b,
                                                 __hip_bfloat16* __restrict__ out) {
  int row = blockIdx.x;
  int tid = threadIdx.x;
  const float* xr = X + (size_t)row * DD;
  float4 v = *(const float4*)&xr[tid * 4];
  float s = v.x + v.y + v.z + v.w;
  float s2 = v.x * v.x + v.y * v.y + v.z * v.z + v.w * v.w;
#pragma unroll
  for (int m = 1; m < 64; m <<= 1) {
    s += __shfl_xor(s, m);
    s2 += __shfl_xor(s2, m);
  }
  __shared__ float ps[4], ps2[4];
  int wv_ = tid >> 6, lane = tid & 63;
  if (lane == 0) { ps[wv_] = s; ps2[wv_] = s2; }
  __syncthreads();
  float ts = ps[0] + ps[1] + ps[2] + ps[3];
  float ts2 = ps2[0] + ps2[1] + ps2[2] + ps2[3];
  float mu = ts * (1.0f / DD);
  float var = ts2 * (1.0f / DD) - mu * mu;
  float rs = rsqrtf(var + 1e-5f);
  float4 wv = *(const float4*)&w[tid * 4];
  float4 bv = *(const float4*)&b[tid * 4];
  __hip_bfloat16 o[4];
  o[0] = __float2bfloat16((v.x - mu) * rs * wv.x + bv.x);
  o[1] = __float2bfloat16((v.y - mu) * rs * wv.y + bv.y);
  o[2] = __float2bfloat16((v.z - mu) * rs * wv.z + bv.z);
  o[3] = __float2bfloat16((v.w - mu) * rs * wv.w + bv.w);
  *(uint2*)&out[(size_t)row * DD + tid * 4] = *(const uint2*)o;
}

// ===================== 256x256 8-phase GEMM (T1+T2+T3+T4+T5) =====================
template <int EPI>
__global__ __launch_bounds__(512) void gemm256(const __hip_bfloat16* __restrict__ A,
                                               const __hip_bfloat16* __restrict__ Bt,
                                               const float* __restrict__ bias,
                                               const float* __restrict__ resid,
                                               void* __restrict__ Cout,
                                               int M, int N, int K) {
  __shared__ __hip_bfloat16 Ab[2][2][128][64];
  __shared__ __hip_bfloat16 Bb[2][2][128][64];
  const int tid = threadIdx.x, lane = tid & 63, w = tid >> 6;
  const int wm = w >> 2, wn = w & 3;

  int nbx = gridDim.x, nwg = nbx * gridDim.y;
  int orig = blockIdx.y * nbx + blockIdx.x;
  int cpx = nwg >> 3;
  int wgid = (orig & 7) * cpx + (orig >> 3);
  int bm0 = (wgid / nbx) * 256, bn0 = (wgid % nbx) * 256;

  const int srow = lane >> 3;
  const int scol = ((lane & 7) ^ srow) * 8;
  const int fr = lane & 15, kq = lane >> 4;

  auto stageA = [&](int d, int half, int k0) {
    const __hip_bfloat16* g0 =
        A + (size_t)(bm0 + half * 128 + w * 16 + srow) * K + k0 + scol;
    char* dst = (char*)&Ab[d][half][0][0] + w * 2048;
    GLOAD16(g0, dst);
    GLOAD16(g0 + (size_t)8 * K, dst + 1024);
  };
  auto stageB = [&](int d, int half, int k0) {
    const __hip_bfloat16* g0 =
        Bt + (size_t)(bn0 + half * 128 + w * 16 + srow) * K + k0 + scol;
    char* dst = (char*)&Bb[d][half][0][0] + w * 2048;
    GLOAD16(g0, dst);
    GLOAD16(g0 + (size_t)8 * K, dst + 1024);
  };
  auto ldA = [&](int d, int r, int ks) -> bf16x8 {
    int byte = r * 128 + (((ks * 32 + kq * 8) * 2) ^ ((r & 7) << 4));
    return *(const bf16x8*)((const char*)&Ab[d][wm][0][0] + byte);
  };
  auto ldB = [&](int d, int r, int ks) -> bf16x8 {
    int byte = r * 128 + (((ks * 32 + kq * 8) * 2) ^ ((r & 7) << 4));
    return *(const bf16x8*)((const char*)&Bb[d][wn >> 1][0][0] + byte);
  };

  f32x4 acc[8][4] = {};
  bf16x8 a0[8], a1[8], b0[4], b1[4];

  auto rdA = [&](bf16x8* dst, int d, int mfb) {
#pragma unroll
    for (int mf = 0; mf < 4; ++mf)
#pragma unroll
      for (int ks = 0; ks < 2; ++ks)
        dst[mf * 2 + ks] = ldA(d, (mfb + mf) * 16 + fr, ks);
  };
  auto rdB = [&](bf16x8* dst, int d, int nfb) {
#pragma unroll
    for (int nf = 0; nf < 2; ++nf)
#pragma unroll
      for (int ks = 0; ks < 2; ++ks)
        dst[nf * 2 + ks] = ldB(d, (wn & 1) * 64 + (nfb + nf) * 16 + fr, ks);
  };
  auto mmq = [&](int mo, int no, bf16x8* ar, bf16x8* br) {
    __builtin_amdgcn_s_setprio(1);
#pragma unroll
    for (int mf = 0; mf < 4; ++mf)
#pragma unroll
      for (int nf = 0; nf < 2; ++nf)
#pragma unroll
        for (int ks = 0; ks < 2; ++ks)
          acc[mo + mf][no + nf] = __builtin_amdgcn_mfma_f32_16x16x32_bf16(
              ar[mf * 2 + ks], br[nf * 2 + ks], acc[mo + mf][no + nf], 0, 0, 0);
    __builtin_amdgcn_s_setprio(0);
  };

  stageA(0, 0, 0); stageA(0, 1, 0);
  stageB(0, 0, 0); stageB(0, 1, 0);
  stageA(1, 0, 64); stageA(1, 1, 64);
  asm volatile("s_waitcnt vmcnt(4)" ::: "memory");
  BARRIER;

  const int niter = (K >> 6) >> 1;
  for (int i = 0; i < niter; ++i) {
    const bool last = (i == niter - 1);
    const int k1 = (2 * i + 1) * 64, k2 = (2 * i + 2) * 64, k3 = (2 * i + 3) * 64;
    rdA(a0, 0, 0); rdB(b0, 0, 0);
    stageB(1, 0, k1);
    BARRIER; SCHEDB; mmq(0, 0, a0, b0); SCHEDB; BARRIER;
    rdA(a1, 0, 4);
    stageB(1, 1, k1);
    BARRIER; SCHEDB; mmq(4, 0, a1, b0); SCHEDB; BARRIER;
    rdB(b1, 0, 2);
    if (!last) stageA(0, 0, k2);
    BARRIER; SCHEDB; mmq(0, 2, a0, b1); SCHEDB; BARRIER;
    if (!last) stageA(0, 1, k2);
    BARRIER; SCHEDB; mmq(4, 2, a1, b1); SCHEDB;
    if (last) { asm volatile("s_waitcnt vmcnt(0)" ::: "memory"); }
    else      { asm volatile("s_waitcnt vmcnt(4)" ::: "memory"); }
    BARRIER;
    rdA(a0, 1, 0); rdB(b0, 1, 0);
    if (!last) stageB(0, 0, k2);
    BARRIER; SCHEDB; mmq(0, 0, a0, b0); SCHEDB; BARRIER;
    rdA(a1, 1, 4);
    if (!last) stageB(0, 1, k2);
    BARRIER; SCHEDB; mmq(4, 0, a1, b0); SCHEDB; BARRIER;
    rdB(b1, 1, 2);
    if (!last) stageA(1, 0, k3);
    BARRIER; SCHEDB; mmq(0, 2, a0, b1); SCHEDB; BARRIER;
    if (!last) stageA(1, 1, k3);
    BARRIER; SCHEDB; mmq(4, 2, a1, b1); SCHEDB;
    if (last) { asm volatile("s_waitcnt vmcnt(0)" ::: "memory"); }
    else      { asm volatile("s_waitcnt vmcnt(4)" ::: "memory"); }
    BARRIER;
  }

#pragma unroll
  for (int nf = 0; nf < 4; ++nf) {
    int col = bn0 + wn * 64 + nf * 16 + fr;
    float bsv = bias[col];
#pragma unroll
    for (int mf = 0; mf < 8; ++mf) {
      int rowb = bm0 + wm * 128 + mf * 16 + (lane >> 4) * 4;
#pragma unroll
      for (int j = 0; j < 4; ++j) {
        int row = rowb + j;
        float v = acc[mf][nf][j] + bsv;
        if (EPI == 1) v = 0.5f * v * (1.0f + erff(v * 0.7071067811865476f));
        if (EPI == 2) {
          ((float*)Cout)[(size_t)row * N + col] = v + resid[(size_t)row * N + col];
        } else {
          ((__hip_bfloat16*)Cout)[(size_t)row * N + col] = __float2bfloat16(v);
        }
      }
    }
  }
}

// ===================== 128x128 4-phase GEMM (narrow-N variant) =====================
template <int EPI>
__global__ __launch_bounds__(256) void gemm128p(const __hip_bfloat16* __restrict__ A,
                                                const __hip_bfloat16* __restrict__ Bt,
                                                const float* __restrict__ bias,
                                                const float* __restrict__ resid,
                                                void* __restrict__ Cout,
                                                int M, int N, int K) {
  __shared__ __hip_bfloat16 Ab[2][2][64][64];
  __shared__ __hip_bfloat16 Bb[2][2][64][64];
  const int tid = threadIdx.x, lane = tid & 63, w = tid >> 6;
  const int wm = w >> 1, wn = w & 1;

  int nbx = gridDim.x, nwg = nbx * gridDim.y;
  int orig = blockIdx.y * nbx + blockIdx.x;
  int cpx = nwg >> 3;
  int wgid = (orig & 7) * cpx + (orig >> 3);
  int bm0 = (wgid / nbx) * 128, bn0 = (wgid % nbx) * 128;

  const int srow = lane >> 3;
  const int scol = ((lane & 7) ^ srow) * 8;
  const int fr = lane & 15, kq = lane >> 4;

  auto stageA = [&](int d, int half, int k0) {
    const __hip_bfloat16* g0 =
        A + (size_t)(bm0 + half * 64 + w * 16 + srow) * K + k0 + scol;
    char* dst = (char*)&Ab[d][half][0][0] + w * 2048;
    GLOAD16(g0, dst);
    GLOAD16(g0 + (size_t)8 * K, dst + 1024);
  };
  auto stageB = [&](int d, int half, int k0) {
    const __hip_bfloat16* g0 =
        Bt + (size_t)(bn0 + half * 64 + w * 16 + srow) * K + k0 + scol;
    char* dst = (char*)&Bb[d][half][0][0] + w * 2048;
    GLOAD16(g0, dst);
    GLOAD16(g0 + (size_t)8 * K, dst + 1024);
  };
  auto ldA = [&](int d, int r, int ks) -> bf16x8 {
    int byte = r * 128 + (((ks * 32 + kq * 8) * 2) ^ ((r & 7) << 4));
    return *(const bf16x8*)((const char*)&Ab[d][wm][0][0] + byte);
  };
  auto ldB = [&](int d, int r, int ks) -> bf16x8 {
    int byte = r * 128 + (((ks * 32 + kq * 8) * 2) ^ ((r & 7) << 4));
    return *(const bf16x8*)((const char*)&Bb[d][wn][0][0] + byte);
  };

  f32x4 acc[4][4] = {};
  bf16x8 aA[8], b0[4], b1[4];

  auto rdA = [&](int d) {
#pragma unroll
    for (int mf = 0; mf < 4; ++mf)
#pragma unroll
      for (int ks = 0; ks < 2; ++ks)
        aA[mf * 2 + ks] = ldA(d, mf * 16 + fr, ks);
  };
  auto rdB = [&](bf16x8* dst, int d, int nfb) {
#pragma unroll
    for (int nf = 0; nf < 2; ++nf)
#pragma unroll
      for (int ks = 0; ks < 2; ++ks)
        dst[nf * 2 + ks] = ldB(d, (nfb + nf) * 16 + fr, ks);
  };
  auto mmq = [&](int no, bf16x8* br) {
    __builtin_amdgcn_s_setprio(1);
#pragma unroll
    for (int mf = 0; mf < 4; ++mf)
#pragma unroll
      for (int nf = 0; nf < 2; ++nf)
#pragma unroll
        for (int ks = 0; ks < 2; ++ks)
          acc[mf][no + nf] = __builtin_amdgcn_mfma_f32_16x16x32_bf16(
              aA[mf * 2 + ks], br[nf * 2 + ks], acc[mf][no + nf], 0, 0, 0);
    __builtin_amdgcn_s_setprio(0);
  };

  stageA(0, 0, 0); stageA(0, 1, 0);
  stageB(0, 0, 0); stageB(0, 1, 0);
  stageA(1, 0, 64); stageA(1, 1, 64);
  asm volatile("s_waitcnt vmcnt(4)" ::: "memory");
  BARRIER;

  const int niter = (K >> 6) >> 1;
  for (int i = 0; i < niter; ++i) {
    const bool last = (i == niter - 1);
    const int k1 = (2 * i + 1) * 64, k2 = (2 * i + 2) * 64, k3 = (2 * i + 3) * 64;
    rdA(0); rdB(b0, 0, 0);
    stageB(1, 0, k1); stageB(1, 1, k1);
    BARRIER; SCHEDB; mmq(0, b0); SCHEDB; BARRIER;
    rdB(b1, 0, 2);
    if (!last) { stageA(0, 0, k2); stageA(0, 1, k2); }
    BARRIER; SCHEDB; mmq(2, b1); SCHEDB;
    if (last) { asm volatile("s_waitcnt vmcnt(0)" ::: "memory"); }
    else      { asm volatile("s_waitcnt vmcnt(4)" ::: "memory"); }
    BARRIER;
    rdA(1); rdB(b0, 1, 0);
    if (!last) { stageB(0, 0, k2); stageB(0, 1, k2); }
    BARRIER; SCHEDB; mmq(0, b0); SCHEDB; BARRIER;
    rdB(b1, 1, 2);
    if (!last) { stageA(1, 0, k3); stageA(1, 1, k3); }
    BARRIER; SCHEDB; mmq(2, b1); SCHEDB;
    if (last) { asm volatile("s_waitcnt vmcnt(0)" ::: "memory"); }
    else      { asm volatile("s_waitcnt vmcnt(4)" ::: "memory"); }
    BARRIER;
  }

#pragma unroll
  for (int nf = 0; nf < 4; ++nf) {
    int col = bn0 + wn * 64 + nf * 16 + fr;
    float bsv = bias[col];
#pragma unroll
    for (int mf = 0; mf < 4; ++mf) {
      int rowb = bm0 + wm * 64 + mf * 16 + (lane >> 4) * 4;
#pragma unroll
      for (int j = 0; j < 4; ++j) {
        int row = rowb + j;
        float v = acc[mf][nf][j] + bsv;
        if (EPI == 1) v = 0.5f * v * (1.0f + erff(v * 0.7071067811865476f));
        if (EPI == 2) {
          ((float*)Cout)[(size_t)row * N + col] = v + resid[(size_t)row * N + col];
        } else {
          ((__hip_bfloat16*)Cout)[(size_t)row * N + col] = __float2bfloat16(v);
        }
      }
    }
  }
}

// ---------------- MFMA flash attention, T14 async staging + rolling skew band ----------------
// Band identity: m = 960 - l0 + gcol; tile t reads gcols [t*64, t*64+126].
// Chunk C_j = gcols [j*64, j*64+63] lives in er_s/g_s half (j&1); tile t computes C_{t+1}
// (t=0 additionally computes C_0). Softmax reads g_s[w][r][(t*64+jj)&127].
__global__ __launch_bounds__(256) void attn_mfma(const __hip_bfloat16* __restrict__ qkv,
                                                 const __hip_bfloat16* __restrict__ Erb,
                                                 __hip_bfloat16* __restrict__ Y) {
  __shared__ __hip_bfloat16 k_s[64][72];
  __shared__ __hip_bfloat16 er_s[128][72];
  __shared__ __hip_bfloat16 p_s[4][16][72];
  __shared__ __hip_bfloat16 g_s[4][16][128];
  __shared__ __hip_bfloat16 vt_s[64 * 64];  // transposed V, XOR-swizzled

  int bid = blockIdx.x;
  int qi = 15 - (bid >> 6);   // heavy q-tiles first
  int head = bid & 63;
  int h = head & 15, b = head >> 4;
  int l0 = qi * 64;
  int tid = threadIdx.x, lane = tid & 63, w = tid >> 6;
  const int fr = lane & 15, kq = lane >> 4;

  const __hip_bfloat16* base = qkv + (size_t)b * (LL * 3072) + h * 64;

  // Q fragments direct from global (no LDS round-trip)
  bf16x8 qf[2];
  {
    const __hip_bfloat16* q0 = base + (size_t)(l0 + 16 * w + fr) * 3072 + kq * 8;
    qf[0] = *(const bf16x8*)q0;
    qf[1] = *(const bf16x8*)(q0 + 32);
  }

  // staging thread maps (loop-invariant)
  const int ksr = tid >> 2, ksd = (tid & 3) * 16;
  const __hip_bfloat16* ksrc = base + 1024 + (size_t)ksr * 3072 + ksd;
  const int vc = (tid >> 3) * 2, vd0 = (tid & 7) * 8;
  const __hip_bfloat16* vsrc = base + 2048 + (size_t)vc * 3072 + vd0;
  const int e0r = tid >> 1, e0c = (tid & 1) * 32;  // 128-row map (t==0)
  const int err = tid >> 2, erc = (tid & 3) * 16;  // 64-row rolling map

  uint4 kst0, kst1, vst0, vst1;
  uint4 est0, est1, est2, est3;  // full band (t==0)
  uint4 ers0, ers1;              // rolling band

  {  // prologue issue: tile 0 K/V + full Er band (C0,C1)
    kst0 = *(const uint4*)ksrc; kst1 = *(const uint4*)(ksrc + 8);
    vst0 = *(const uint4*)vsrc; vst1 = *(const uint4*)(vsrc + 3072);
    int m = min(max(960 - l0 + e0r, 0), 1023);
    const __hip_bfloat16* ep = Erb + (size_t)m * 64 + e0c;
    est0 = *(const uint4*)ep;        est1 = *(const uint4*)(ep + 8);
    est2 = *(const uint4*)(ep + 16); est3 = *(const uint4*)(ep + 24);
  }

  f32x4 oacc[4] = {};
  float m_run[4], s_run[4];
#pragma unroll
  for (int j = 0; j < 4; ++j) { m_run[j] = -1e30f; s_run[j] = 0.f; }

  // G-chunk compute: 4 groups over er half hf -> g_s cols hf*64..+63
  auto gchunk = [&](int hf) {
#pragma unroll
    for (int g = 0; g < 4; ++g) {
      int cc = hf * 64 + 16 * g + fr, kc = kq * 8;
      bf16x8 e0 = *(const bf16x8*)&er_s[cc][kc];
      bf16x8 e1 = *(const bf16x8*)&er_s[cc][kc + 32];
      f32x4 gacc = {};
      gacc = __builtin_amdgcn_mfma_f32_16x16x32_bf16(qf[0], e0, gacc, 0, 0, 0);
      gacc = __builtin_amdgcn_mfma_f32_16x16x32_bf16(qf[1], e1, gacc, 0, 0, 0);
#pragma unroll
      for (int j = 0; j < 4; ++j)
        g_s[w][kq * 4 + j][hf * 64 + 16 * g + fr] = __float2bfloat16(gacc[j]);
    }
  };

  for (int t = 0; t <= qi; ++t) {
    __syncthreads();  // (a): drains vmcnt -> staged regs valid; prior-tile LDS reads done
    // ---- write staging to LDS ----
    *(uint4*)&k_s[ksr][ksd] = kst0;
    *(uint4*)&k_s[ksr][ksd + 8] = kst1;
    {
      const uint16_t* h0 = (const uint16_t*)&vst0;
      const uint16_t* h1 = (const uint16_t*)&vst1;
#pragma unroll
      for (int j = 0; j < 8; ++j) {
        int d = vd0 + j;
        uint32_t pk = (uint32_t)h0[j] | ((uint32_t)h1[j] << 16);
        uint32_t byte = ((uint32_t)d << 7) + 2u * (uint32_t)vc;
        byte ^= (uint32_t)(((d & 7) ^ (d >> 3)) << 4);
        *(uint32_t*)((char*)vt_s + byte) = pk;
      }
    }
    if (t == 0) {
      *(uint4*)&er_s[e0r][e0c]      = est0;
      *(uint4*)&er_s[e0r][e0c + 8]  = est1;
      *(uint4*)&er_s[e0r][e0c + 16] = est2;
      *(uint4*)&er_s[e0r][e0c + 24] = est3;
    } else if (t < qi) {
      int hf = (t + 1) & 1;
      *(uint4*)&er_s[hf * 64 + err][erc]     = ers0;
      *(uint4*)&er_s[hf * 64 + err][erc + 8] = ers1;
    }
    __syncthreads();  // (b): staging visible
    // ---- issue next tile's loads (latency hides under compute) ----
    if (t < qi) {
      int c0n = (t + 1) * 64;
      const __hip_bfloat16* kp = ksrc + (size_t)c0n * 3072;
      kst0 = *(const uint4*)kp; kst1 = *(const uint4*)(kp + 8);
      const __hip_bfloat16* vp = vsrc + (size_t)c0n * 3072;
      vst0 = *(const uint4*)vp; vst1 = *(const uint4*)(vp + 3072);
      if (t + 1 < qi) {  // tile t+1 stages chunk C_{t+2}
        int m = min(960 - l0 + (t + 2) * 64 + err, 1023);
        const __hip_bfloat16* ep = Erb + (size_t)m * 64 + erc;
        ers0 = *(const uint4*)ep; ers1 = *(const uint4*)(ep + 8);
      }
    }
    SCHEDB;

    // ---- S = Q K^T ----
    f32x4 sacc[4] = {};
#pragma unroll
    for (int f = 0; f < 4; ++f) {
      int cc = 16 * f + fr, kc = kq * 8;
      bf16x8 k0 = *(const bf16x8*)&k_s[cc][kc];
      bf16x8 k1 = *(const bf16x8*)&k_s[cc][kc + 32];
      sacc[f] = __builtin_amdgcn_mfma_f32_16x16x32_bf16(qf[0], k0, sacc[f], 0, 0, 0);
      sacc[f] = __builtin_amdgcn_mfma_f32_16x16x32_bf16(qf[1], k1, sacc[f], 0, 0, 0);
    }
    // ---- G chunks (rolling band) ----
    if (t == 0) {
      gchunk(0);
      if (qi > 0) gchunk(1);
    } else if (t < qi) {
      gchunk((t + 1) & 1);
    }

    // ---- softmax (online) ----
    float sv[4][4];
#pragma unroll
    for (int f = 0; f < 4; ++f) {
#pragma unroll
      for (int j = 0; j < 4; ++j) {
        int r = kq * 4 + j;
        int c = 16 * f + fr;
        int jj = c - (16 * w + r) + 63;
        float g = __bfloat162float(g_s[w][r][(t * 64 + jj) & 127]);
        float val = (sacc[f][j] + g) * 0.125f;
        if (t == qi && c > 16 * w + r) val = -1e30f;
        sv[f][j] = val;
      }
    }
    float alpha[4];
#pragma unroll
    for (int j = 0; j < 4; ++j) {
      float tm = fmaxf(fmaxf(sv[0][j], sv[1][j]), fmaxf(sv[2][j], sv[3][j]));
      tm = fmaxf(tm, __shfl_xor(tm, 1));
      tm = fmaxf(tm, __shfl_xor(tm, 2));
      tm = fmaxf(tm, __shfl_xor(tm, 4));
      tm = fmaxf(tm, __shfl_xor(tm, 8));
      float nm = fmaxf(m_run[j], tm);
      alpha[j] = __expf(m_run[j] - nm);
      m_run[j] = nm;
    }
#pragma unroll
    for (int f = 0; f < 4; ++f)
#pragma unroll
      for (int j = 0; j < 4; ++j)
        sv[f][j] = __expf(sv[f][j] - m_run[j]);
#pragma unroll
    for (int j = 0; j < 4; ++j) {
      float ps = sv[0][j] + sv[1][j] + sv[2][j] + sv[3][j];
      ps += __shfl_xor(ps, 1); ps += __shfl_xor(ps, 2);
      ps += __shfl_xor(ps, 4); ps += __shfl_xor(ps, 8);
      s_run[j] = s_run[j] * alpha[j] + ps;
    }
#pragma unroll
    for (int f = 0; f < 4; ++f)
#pragma unroll
      for (int j = 0; j < 4; ++j)
        oacc[f][j] *= alpha[j];
#pragma unroll
    for (int f = 0; f < 4; ++f)
#pragma unroll
      for (int j = 0; j < 4; ++j)
        p_s[w][kq * 4 + j][16 * f + fr] = __float2bfloat16(sv[f][j]);
    // ---- PV ----
#pragma unroll
    for (int kk = 0; kk < 2; ++kk) {
      bf16x8 pf = *(const bf16x8*)&p_s[w][fr][kq * 8 + 32 * kk];
#pragma unroll
      for (int f = 0; f < 4; ++f) {
        int d = 16 * f + fr;
        int cc = kq * 8 + 32 * kk;
        uint32_t byte = ((uint32_t)d << 7) + 2u * (uint32_t)cc;
        byte ^= (uint32_t)(((d & 7) ^ (d >> 3)) << 4);
        bf16x8 vf = *(const bf16x8*)((char*)vt_s + byte);
        oacc[f] = __builtin_amdgcn_mfma_f32_16x16x32_bf16(pf, vf, oacc[f], 0, 0, 0);
      }
    }
  }

#pragma unroll
  for (int f = 0; f < 4; ++f)
#pragma unroll
    for (int j = 0; j < 4; ++j) {
      int r = 16 * w + kq * 4 + j;
      int d = 16 * f + fr;
      float o = oacc[f][j] / s_run[j];
      Y[(size_t)(b * LL + l0 + r) * DD + h * 64 + d] = __float2bfloat16(o);
    }
}

// ---------------- launch ----------------
extern "C" void kernel_launch(void* const* d_in, const int* in_sizes, int n_in,
                              void* d_out, int out_size, void* d_ws, size_t ws_size,
                              hipStream_t stream) {
  (void)in_sizes; (void)n_in; (void)out_size; (void)ws_size;
  const float* x     = (const float*)d_in[0];
  const float* ln1w  = (const float*)d_in[1];
  const float* ln1b  = (const float*)d_in[2];
  const float* Wqkv  = (const float*)d_in[3];
  const float* bqkv  = (const float*)d_in[4];
  const float* Wproj = (const float*)d_in[5];
  const float* bproj = (const float*)d_in[6];
  const float* Er    = (const float*)d_in[7];
  const float* ln2w  = (const float*)d_in[8];
  const float* ln2b  = (const float*)d_in[9];
  const float* Wfc   = (const float*)d_in[10];
  const float* bfc   = (const float*)d_in[11];
  const float* Wfc2  = (const float*)d_in[12];
  const float* bfc2  = (const float*)d_in[13];
  float* out = (float*)d_out;

  char* ws = (char*)d_ws;
  const size_t MB = 1ull << 20;
  __hip_bfloat16* h1    = (__hip_bfloat16*)(ws + 0);        // 8 MB
  __hip_bfloat16* qkvb  = (__hip_bfloat16*)(ws + 8 * MB);   // 24 MB
  __hip_bfloat16* mbuf  = (__hip_bfloat16*)(ws + 0);        // 32 MB (aliases h1+qkvb)
  __hip_bfloat16* yb    = (__hip_bfloat16*)(ws + 32 * MB);  // 8 MB
  __hip_bfloat16* h2    = (__hip_bfloat16*)(ws + 32 * MB);  // 8 MB (aliases yb)
  float*          x2    = (float*)(ws + 40 * MB);           // 16 MB
  __hip_bfloat16* Wqkvt = (__hip_bfloat16*)(ws + 56 * MB);  // 6 MB
  __hip_bfloat16* Erb   = (__hip_bfloat16*)(ws + 62 * MB);  // 128 KB
  __hip_bfloat16* Wprojt= (__hip_bfloat16*)(ws + 63 * MB);  // 2 MB
  __hip_bfloat16* Wfct  = (__hip_bfloat16*)(ws + 66 * MB);  // 8 MB
  __hip_bfloat16* Wfc2t = (__hip_bfloat16*)(ws + 75 * MB);  // 8 MB

  dim3 blk(256);

  transpose_cvt<<<dim3(3072 / 32, 1024 / 32), blk, 0, stream>>>(Wqkv, Wqkvt, 1024, 3072);
  transpose_cvt<<<dim3(1024 / 32, 1024 / 32), blk, 0, stream>>>(Wproj, Wprojt, 1024, 1024);
  transpose_cvt<<<dim3(4096 / 32, 1024 / 32), blk, 0, stream>>>(Wfc, Wfct, 1024, 4096);
  transpose_cvt<<<dim3(1024 / 32, 4096 / 32), blk, 0, stream>>>(Wfc2, Wfc2t, 4096, 1024);
  cvt_er<<<dim3(64), blk, 0, stream>>>(Er, Erb);

  ln_kernel<<<4096, blk, 0, stream>>>(x, ln1w, ln1b, h1);

  gemm256<0><<<dim3(3072 / 256, 4096 / 256), dim3(512), 0, stream>>>(
      h1, Wqkvt, bqkv, nullptr, qkvb, 4096, 3072, 1024);

  attn_mfma<<<dim3(1024), blk, 0, stream>>>(qkvb, Erb, yb);

  gemm128p<2><<<dim3(1024 / 128, 4096 / 128), blk, 0, stream>>>(
      yb, Wprojt, bproj, x, x2, 4096, 1024, 1024);

  ln_kernel<<<4096, blk, 0, stream>>>(x2, ln2w, ln2b, h2);

  gemm256<1><<<dim3(4096 / 256, 4096 / 256), dim3(512), 0, stream>>>(
      h2, Wfct, bfc, nullptr, mbuf, 4096, 4096, 1024);

  gemm128p<2><<<dim3(1024 / 128, 4096 / 128), blk, 0, stream>>>(
      mbuf, Wfc2t, bfc2, x2, out, 4096, 1024, 4096);
}

// Round 10
// 255.478 us; speedup vs baseline: 4.8605x; 1.0250x over previous
//
#include <hip/hip_runtime.h>
#include <hip/hip_bf16.h>
#include <math.h>

typedef __attribute__((ext_vector_type(8))) __bf16 bf16x8;
typedef __attribute__((ext_vector_type(4))) float f32x4;

#define LL 1024
#define DD 1024
#define HH 16

#define GLOAD16(g, l)                                              \
  __builtin_amdgcn_global_load_lds(                                \
      (const __attribute__((address_space(1))) void*)(g),          \
      (__attribute__((address_space(3))) void*)(l), 16, 0, 0)

#define FENCE asm volatile("" ::: "memory")
#define BARRIER do { FENCE; __builtin_amdgcn_s_barrier(); FENCE; } while (0)
#define SCHEDB __builtin_amdgcn_sched_barrier(0)

// ---------------- weight transpose + fp32->bf16 ----------------
__global__ __launch_bounds__(256) void transpose_cvt(const float* __restrict__ W,
                                                     __hip_bfloat16* __restrict__ Wt,
                                                     int R, int C) {
  __shared__ float tile[32][33];
  int tx = threadIdx.x;
  int r0 = blockIdx.y * 32, c0 = blockIdx.x * 32;
  int r = tx >> 3, c4 = (tx & 7) * 4;
  float4 v = *(const float4*)&W[(size_t)(r0 + r) * C + c0 + c4];
  tile[r][c4 + 0] = v.x; tile[r][c4 + 1] = v.y;
  tile[r][c4 + 2] = v.z; tile[r][c4 + 3] = v.w;
  __syncthreads();
  int c = tx >> 3, r4 = (tx & 7) * 4;
  __hip_bfloat16 o[4];
#pragma unroll
  for (int j = 0; j < 4; ++j) o[j] = __float2bfloat16(tile[r4 + j][c]);
  *(uint2*)&Wt[(size_t)(c0 + c) * R + r0 + r4] = *(const uint2*)o;
}

// ---------------- Er fp32 -> bf16 (once) ----------------
__global__ __launch_bounds__(256) void cvt_er(const float* __restrict__ Er,
                                              __hip_bfloat16* __restrict__ Erb) {
  int i = blockIdx.x * 256 + threadIdx.x;
  float4 v = *(const float4*)&Er[(size_t)i * 4];
  __hip_bfloat16 o[4];
  o[0] = __float2bfloat16(v.x); o[1] = __float2bfloat16(v.y);
  o[2] = __float2bfloat16(v.z); o[3] = __float2bfloat16(v.w);
  *(uint2*)&Erb[(size_t)i * 4] = *(const uint2*)o;
}

// ---------------- layernorm (fp32 in -> bf16 out) ----------------
__global__ __launch_bounds__(256) void ln_kernel(const float* __restrict__ X,
                                                 const float* __restrict__ w,
                                                 const float* __restrict__ b,
                                                 __hip_bfloat16* __restrict__ out) {
  int row = blockIdx.x;
  int tid = threadIdx.x;
  const float* xr = X + (size_t)row * DD;
  float4 v = *(const float4*)&xr[tid * 4];
  float s = v.x + v.y + v.z + v.w;
  float s2 = v.x * v.x + v.y * v.y + v.z * v.z + v.w * v.w;
#pragma unroll
  for (int m = 1; m < 64; m <<= 1) {
    s += __shfl_xor(s, m);
    s2 += __shfl_xor(s2, m);
  }
  __shared__ float ps[4], ps2[4];
  int wv_ = tid >> 6, lane = tid & 63;
  if (lane == 0) { ps[wv_] = s; ps2[wv_] = s2; }
  __syncthreads();
  float ts = ps[0] + ps[1] + ps[2] + ps[3];
  float ts2 = ps2[0] + ps2[1] + ps2[2] + ps2[3];
  float mu = ts * (1.0f / DD);
  float var = ts2 * (1.0f / DD) - mu * mu;
  float rs = rsqrtf(var + 1e-5f);
  float4 wv = *(const float4*)&w[tid * 4];
  float4 bv = *(const float4*)&b[tid * 4];
  __hip_bfloat16 o[4];
  o[0] = __float2bfloat16((v.x - mu) * rs * wv.x + bv.x);
  o[1] = __float2bfloat16((v.y - mu) * rs * wv.y + bv.y);
  o[2] = __float2bfloat16((v.z - mu) * rs * wv.z + bv.z);
  o[3] = __float2bfloat16((v.w - mu) * rs * wv.w + bv.w);
  *(uint2*)&out[(size_t)row * DD + tid * 4] = *(const uint2*)o;
}

// ===================== 256x256 GEMM, BK=32, quad-buffered deep pipeline =====================
// 8 waves (2M x 4N), per-wave out 128x64. Iteration t computes K-tile t (buf t&3),
// stages tile t+3; end-of-iter vmcnt(8) completes tile t+1 (staged 4-5 phases earlier).
// Swizzle (64B rows): slot = kq ^ ((row>>1)&3); source pre-inverse-swizzled.
template <int EPI>
__global__ __launch_bounds__(512) void gemm256(const __hip_bfloat16* __restrict__ A,
                                               const __hip_bfloat16* __restrict__ Bt,
                                               const float* __restrict__ bias,
                                               const float* __restrict__ resid,
                                               void* __restrict__ Cout,
                                               int M, int N, int K) {
  __shared__ __hip_bfloat16 Ab[4][256][32];  // 4 x 16KB
  __shared__ __hip_bfloat16 Bb[4][256][32];  // 4 x 16KB
  const int tid = threadIdx.x, lane = tid & 63, w = tid >> 6;
  const int wm = w >> 2, wn = w & 3;

  int nbx = gridDim.x, nwg = nbx * gridDim.y;
  int orig = blockIdx.y * nbx + blockIdx.x;
  int cpx = nwg >> 3;
  int wgid = (orig & 7) * cpx + (orig >> 3);   // grids are %8==0
  int bm0 = (wgid / nbx) * 256, bn0 = (wgid % nbx) * 256;

  const int fr = lane & 15, kq = lane >> 4;
  const int sg = ((lane & 3) ^ ((lane >> 3) & 3)) * 8;  // inverse-swizzled col (elems)
  const int srw = lane >> 2;                            // row within 128-half / wave*16

  auto stageA = [&](int c, int half, int k0) {
    const __hip_bfloat16* src =
        A + (size_t)(bm0 + half * 128 + w * 16 + srw) * K + k0 + sg;
    GLOAD16(src, (char*)Ab + c * 16384 + half * 8192 + w * 1024);
  };
  auto stageB = [&](int c, int half, int k0) {
    const __hip_bfloat16* src =
        Bt + (size_t)(bn0 + half * 128 + w * 16 + srw) * K + k0 + sg;
    GLOAD16(src, (char*)Bb + c * 16384 + half * 8192 + w * 1024);
  };
  const int swz = ((kq ^ ((fr >> 1) & 3)) << 4);
  auto ldA = [&](int c, int r) -> bf16x8 {
    return *(const bf16x8*)((const char*)Ab + c * 16384 + r * 64 + swz);
  };
  auto ldB = [&](int c, int r) -> bf16x8 {
    return *(const bf16x8*)((const char*)Bb + c * 16384 + r * 64 + swz);
  };

  f32x4 acc[8][4] = {};
  bf16x8 a[8], b0[2], b1[2];

  auto mm16 = [&](int no, bf16x8* br) {
    __builtin_amdgcn_s_setprio(1);
#pragma unroll
    for (int mf = 0; mf < 8; ++mf)
#pragma unroll
      for (int nf = 0; nf < 2; ++nf)
        acc[mf][no + nf] = __builtin_amdgcn_mfma_f32_16x16x32_bf16(
            a[mf], br[nf], acc[mf][no + nf], 0, 0, 0);
    __builtin_amdgcn_s_setprio(0);
  };

  const int nt = K >> 5;
  // prologue: tiles 0,1,2 (12 loads); vmcnt(8) -> tile0 landed
#pragma unroll
  for (int tt = 0; tt < 3; ++tt) {
    stageA(tt, 0, tt * 32); stageA(tt, 1, tt * 32);
    stageB(tt, 0, tt * 32); stageB(tt, 1, tt * 32);
  }
  asm volatile("s_waitcnt vmcnt(8)" ::: "memory");
  BARRIER;

  for (int t = 0; t < nt; ++t) {
    const int cur = t & 3, nxt = (t + 3) & 3, kn = (t + 3) * 32;
    const bool st = (t + 3 < nt);
    // ---- phase 1: A-frags + B lo-quadrant; stage A(t+3) ----
#pragma unroll
    for (int mf = 0; mf < 8; ++mf) a[mf] = ldA(cur, wm * 128 + mf * 16 + fr);
#pragma unroll
    for (int nf = 0; nf < 2; ++nf) b0[nf] = ldB(cur, wn * 64 + nf * 16 + fr);
    if (st) { stageA(nxt, 0, kn); stageA(nxt, 1, kn); }
    BARRIER; SCHEDB; mm16(0, b0); SCHEDB; BARRIER;
    // ---- phase 2: B hi-quadrant; stage B(t+3); counted wait ----
#pragma unroll
    for (int nf = 0; nf < 2; ++nf) b1[nf] = ldB(cur, wn * 64 + (nf + 2) * 16 + fr);
    if (st) { stageB(nxt, 0, kn); stageB(nxt, 1, kn); }
    BARRIER; SCHEDB; mm16(2, b1); SCHEDB;
    if (t <= nt - 4)      { asm volatile("s_waitcnt vmcnt(8)" ::: "memory"); }
    else if (t == nt - 3) { asm volatile("s_waitcnt vmcnt(4)" ::: "memory"); }
    else if (t == nt - 2) { asm volatile("s_waitcnt vmcnt(0)" ::: "memory"); }
    BARRIER;
  }

  // epilogue
#pragma unroll
  for (int nf = 0; nf < 4; ++nf) {
    int col = bn0 + wn * 64 + nf * 16 + fr;
    float bsv = bias[col];
#pragma unroll
    for (int mf = 0; mf < 8; ++mf) {
      int rowb = bm0 + wm * 128 + mf * 16 + kq * 4;
#pragma unroll
      for (int j = 0; j < 4; ++j) {
        int row = rowb + j;
        float v = acc[mf][nf][j] + bsv;
        if (EPI == 1) v = 0.5f * v * (1.0f + erff(v * 0.7071067811865476f));
        if (EPI == 2) {
          ((float*)Cout)[(size_t)row * N + col] = v + resid[(size_t)row * N + col];
        } else {
          ((__hip_bfloat16*)Cout)[(size_t)row * N + col] = __float2bfloat16(v);
        }
      }
    }
  }
}

// ===================== 128x128 GEMM, BK=32, penta-buffered deep pipeline =====================
// 4 waves (2M x 2N), per-wave out 64x64. Iteration t (1 phase) computes tile t (buf t%5),
// stages tile t+4; end-of-iter vmcnt(12) completes tile t+1 (lead 3-4 phases).
template <int EPI>
__global__ __launch_bounds__(256) void gemm128p(const __hip_bfloat16* __restrict__ A,
                                                const __hip_bfloat16* __restrict__ Bt,
                                                const float* __restrict__ bias,
                                                const float* __restrict__ resid,
                                                void* __restrict__ Cout,
                                                int M, int N, int K) {
  __shared__ __hip_bfloat16 Ab[5][128][32];  // 5 x 8KB
  __shared__ __hip_bfloat16 Bb[5][128][32];  // 5 x 8KB
  const int tid = threadIdx.x, lane = tid & 63, w = tid >> 6;
  const int wm = w >> 1, wn = w & 1;

  int nbx = gridDim.x, nwg = nbx * gridDim.y;
  int orig = blockIdx.y * nbx + blockIdx.x;
  int cpx = nwg >> 3;
  int wgid = (orig & 7) * cpx + (orig >> 3);
  int bm0 = (wgid / nbx) * 128, bn0 = (wgid % nbx) * 128;

  const int fr = lane & 15, kq = lane >> 4;
  const int sg = ((lane & 3) ^ ((lane >> 3) & 3)) * 8;
  const int srw = lane >> 2;

  auto stageA = [&](int c, int half, int k0) {
    const __hip_bfloat16* src =
        A + (size_t)(bm0 + half * 64 + w * 16 + srw) * K + k0 + sg;
    GLOAD16(src, (char*)Ab + c * 8192 + half * 4096 + w * 1024);
  };
  auto stageB = [&](int c, int half, int k0) {
    const __hip_bfloat16* src =
        Bt + (size_t)(bn0 + half * 64 + w * 16 + srw) * K + k0 + sg;
    GLOAD16(src, (char*)Bb + c * 8192 + half * 4096 + w * 1024);
  };
  const int swz = ((kq ^ ((fr >> 1) & 3)) << 4);
  auto ldA = [&](int c, int r) -> bf16x8 {
    return *(const bf16x8*)((const char*)Ab + c * 8192 + r * 64 + swz);
  };
  auto ldB = [&](int c, int r) -> bf16x8 {
    return *(const bf16x8*)((const char*)Bb + c * 8192 + r * 64 + swz);
  };

  f32x4 acc[4][4] = {};
  bf16x8 a[4], b[4];

  const int nt = K >> 5;
  // prologue: tiles 0..3 (16 loads); vmcnt(12) -> tile0 landed
#pragma unroll
  for (int tt = 0; tt < 4; ++tt) {
    stageA(tt, 0, tt * 32); stageA(tt, 1, tt * 32);
    stageB(tt, 0, tt * 32); stageB(tt, 1, tt * 32);
  }
  asm volatile("s_waitcnt vmcnt(12)" ::: "memory");
  BARRIER;

  int cur = 0, nxt = 4;
  for (int t = 0; t < nt; ++t) {
    const int kn = (t + 4) * 32;
    const bool st = (t + 4 < nt);
#pragma unroll
    for (int mf = 0; mf < 4; ++mf) a[mf] = ldA(cur, wm * 64 + mf * 16 + fr);
#pragma unroll
    for (int nf = 0; nf < 4; ++nf) b[nf] = ldB(cur, wn * 64 + nf * 16 + fr);
    if (st) {
      stageA(nxt, 0, kn); stageA(nxt, 1, kn);
      stageB(nxt, 0, kn); stageB(nxt, 1, kn);
    }
    BARRIER; SCHEDB;
    __builtin_amdgcn_s_setprio(1);
#pragma unroll
    for (int mf = 0; mf < 4; ++mf)
#pragma unroll
      for (int nf = 0; nf < 4; ++nf)
        acc[mf][nf] = __builtin_amdgcn_mfma_f32_16x16x32_bf16(a[mf], b[nf], acc[mf][nf], 0, 0, 0);
    __builtin_amdgcn_s_setprio(0);
    SCHEDB;
    if (t <= nt - 5)      { asm volatile("s_waitcnt vmcnt(12)" ::: "memory"); }
    else if (t == nt - 4) { asm volatile("s_waitcnt vmcnt(8)" ::: "memory"); }
    else if (t == nt - 3) { asm volatile("s_waitcnt vmcnt(4)" ::: "memory"); }
    else if (t == nt - 2) { asm volatile("s_waitcnt vmcnt(0)" ::: "memory"); }
    BARRIER;
    cur = (cur == 4) ? 0 : cur + 1;
    nxt = (nxt == 4) ? 0 : nxt + 1;
  }

  // epilogue
#pragma unroll
  for (int nf = 0; nf < 4; ++nf) {
    int col = bn0 + wn * 64 + nf * 16 + fr;
    float bsv = bias[col];
#pragma unroll
    for (int mf = 0; mf < 4; ++mf) {
      int rowb = bm0 + wm * 64 + mf * 16 + kq * 4;
#pragma unroll
      for (int j = 0; j < 4; ++j) {
        int row = rowb + j;
        float v = acc[mf][nf][j] + bsv;
        if (EPI == 1) v = 0.5f * v * (1.0f + erff(v * 0.7071067811865476f));
        if (EPI == 2) {
          ((float*)Cout)[(size_t)row * N + col] = v + resid[(size_t)row * N + col];
        } else {
          ((__hip_bfloat16*)Cout)[(size_t)row * N + col] = __float2bfloat16(v);
        }
      }
    }
  }
}

// ---------------- MFMA flash attention, T14 async staging + rolling skew band ----------------
__global__ __launch_bounds__(256) void attn_mfma(const __hip_bfloat16* __restrict__ qkv,
                                                 const __hip_bfloat16* __restrict__ Erb,
                                                 __hip_bfloat16* __restrict__ Y) {
  __shared__ __hip_bfloat16 k_s[64][72];
  __shared__ __hip_bfloat16 er_s[128][72];
  __shared__ __hip_bfloat16 p_s[4][16][72];
  __shared__ __hip_bfloat16 g_s[4][16][128];
  __shared__ __hip_bfloat16 vt_s[64 * 64];

  int bid = blockIdx.x;
  int qi = 15 - (bid >> 6);
  int head = bid & 63;
  int h = head & 15, b = head >> 4;
  int l0 = qi * 64;
  int tid = threadIdx.x, lane = tid & 63, w = tid >> 6;
  const int fr = lane & 15, kq = lane >> 4;

  const __hip_bfloat16* base = qkv + (size_t)b * (LL * 3072) + h * 64;

  bf16x8 qf[2];
  {
    const __hip_bfloat16* q0 = base + (size_t)(l0 + 16 * w + fr) * 3072 + kq * 8;
    qf[0] = *(const bf16x8*)q0;
    qf[1] = *(const bf16x8*)(q0 + 32);
  }

  const int ksr = tid >> 2, ksd = (tid & 3) * 16;
  const __hip_bfloat16* ksrc = base + 1024 + (size_t)ksr * 3072 + ksd;
  const int vc = (tid >> 3) * 2, vd0 = (tid & 7) * 8;
  const __hip_bfloat16* vsrc = base + 2048 + (size_t)vc * 3072 + vd0;
  const int e0r = tid >> 1, e0c = (tid & 1) * 32;
  const int err = tid >> 2, erc = (tid & 3) * 16;

  uint4 kst0, kst1, vst0, vst1;
  uint4 est0, est1, est2, est3;
  uint4 ers0, ers1;

  {
    kst0 = *(const uint4*)ksrc; kst1 = *(const uint4*)(ksrc + 8);
    vst0 = *(const uint4*)vsrc; vst1 = *(const uint4*)(vsrc + 3072);
    int m = min(max(960 - l0 + e0r, 0), 1023);
    const __hip_bfloat16* ep = Erb + (size_t)m * 64 + e0c;
    est0 = *(const uint4*)ep;        est1 = *(const uint4*)(ep + 8);
    est2 = *(const uint4*)(ep + 16); est3 = *(const uint4*)(ep + 24);
  }

  f32x4 oacc[4] = {};
  float m_run[4], s_run[4];
#pragma unroll
  for (int j = 0; j < 4; ++j) { m_run[j] = -1e30f; s_run[j] = 0.f; }

  auto gchunk = [&](int hf) {
#pragma unroll
    for (int g = 0; g < 4; ++g) {
      int cc = hf * 64 + 16 * g + fr, kc = kq * 8;
      bf16x8 e0 = *(const bf16x8*)&er_s[cc][kc];
      bf16x8 e1 = *(const bf16x8*)&er_s[cc][kc + 32];
      f32x4 gacc = {};
      gacc = __builtin_amdgcn_mfma_f32_16x16x32_bf16(qf[0], e0, gacc, 0, 0, 0);
      gacc = __builtin_amdgcn_mfma_f32_16x16x32_bf16(qf[1], e1, gacc, 0, 0, 0);
#pragma unroll
      for (int j = 0; j < 4; ++j)
        g_s[w][kq * 4 + j][hf * 64 + 16 * g + fr] = __float2bfloat16(gacc[j]);
    }
  };

  for (int t = 0; t <= qi; ++t) {
    __syncthreads();
    *(uint4*)&k_s[ksr][ksd] = kst0;
    *(uint4*)&k_s[ksr][ksd + 8] = kst1;
    {
      const uint16_t* h0 = (const uint16_t*)&vst0;
      const uint16_t* h1 = (const uint16_t*)&vst1;
#pragma unroll
      for (int j = 0; j < 8; ++j) {
        int d = vd0 + j;
        uint32_t pk = (uint32_t)h0[j] | ((uint32_t)h1[j] << 16);
        uint32_t byte = ((uint32_t)d << 7) + 2u * (uint32_t)vc;
        byte ^= (uint32_t)(((d & 7) ^ (d >> 3)) << 4);
        *(uint32_t*)((char*)vt_s + byte) = pk;
      }
    }
    if (t == 0) {
      *(uint4*)&er_s[e0r][e0c]      = est0;
      *(uint4*)&er_s[e0r][e0c + 8]  = est1;
      *(uint4*)&er_s[e0r][e0c + 16] = est2;
      *(uint4*)&er_s[e0r][e0c + 24] = est3;
    } else if (t < qi) {
      int hf = (t + 1) & 1;
      *(uint4*)&er_s[hf * 64 + err][erc]     = ers0;
      *(uint4*)&er_s[hf * 64 + err][erc + 8] = ers1;
    }
    __syncthreads();
    if (t < qi) {
      int c0n = (t + 1) * 64;
      const __hip_bfloat16* kp = ksrc + (size_t)c0n * 3072;
      kst0 = *(const uint4*)kp; kst1 = *(const uint4*)(kp + 8);
      const __hip_bfloat16* vp = vsrc + (size_t)c0n * 3072;
      vst0 = *(const uint4*)vp; vst1 = *(const uint4*)(vp + 3072);
      if (t + 1 < qi) {
        int m = min(960 - l0 + (t + 2) * 64 + err, 1023);
        const __hip_bfloat16* ep = Erb + (size_t)m * 64 + erc;
        ers0 = *(const uint4*)ep; ers1 = *(const uint4*)(ep + 8);
      }
    }
    SCHEDB;

    f32x4 sacc[4] = {};
#pragma unroll
    for (int f = 0; f < 4; ++f) {
      int cc = 16 * f + fr, kc = kq * 8;
      bf16x8 k0 = *(const bf16x8*)&k_s[cc][kc];
      bf16x8 k1 = *(const bf16x8*)&k_s[cc][kc + 32];
      sacc[f] = __builtin_amdgcn_mfma_f32_16x16x32_bf16(qf[0], k0, sacc[f], 0, 0, 0);
      sacc[f] = __builtin_amdgcn_mfma_f32_16x16x32_bf16(qf[1], k1, sacc[f], 0, 0, 0);
    }
    if (t == 0) {
      gchunk(0);
      if (qi > 0) gchunk(1);
    } else if (t < qi) {
      gchunk((t + 1) & 1);
    }

    float sv[4][4];
#pragma unroll
    for (int f = 0; f < 4; ++f) {
#pragma unroll
      for (int j = 0; j < 4; ++j) {
        int r = kq * 4 + j;
        int c = 16 * f + fr;
        int jj = c - (16 * w + r) + 63;
        float g = __bfloat162float(g_s[w][r][(t * 64 + jj) & 127]);
        float val = (sacc[f][j] + g) * 0.125f;
        if (t == qi && c > 16 * w + r) val = -1e30f;
        sv[f][j] = val;
      }
    }
    float alpha[4];
#pragma unroll
    for (int j = 0; j < 4; ++j) {
      float tm = fmaxf(fmaxf(sv[0][j], sv[1][j]), fmaxf(sv[2][j], sv[3][j]));
      tm = fmaxf(tm, __shfl_xor(tm, 1));
      tm = fmaxf(tm, __shfl_xor(tm, 2));
      tm = fmaxf(tm, __shfl_xor(tm, 4));
      tm = fmaxf(tm, __shfl_xor(tm, 8));
      float nm = fmaxf(m_run[j], tm);
      alpha[j] = __expf(m_run[j] - nm);
      m_run[j] = nm;
    }
#pragma unroll
    for (int f = 0; f < 4; ++f)
#pragma unroll
      for (int j = 0; j < 4; ++j)
        sv[f][j] = __expf(sv[f][j] - m_run[j]);
#pragma unroll
    for (int j = 0; j < 4; ++j) {
      float ps = sv[0][j] + sv[1][j] + sv[2][j] + sv[3][j];
      ps += __shfl_xor(ps, 1); ps += __shfl_xor(ps, 2);
      ps += __shfl_xor(ps, 4); ps += __shfl_xor(ps, 8);
      s_run[j] = s_run[j] * alpha[j] + ps;
    }
#pragma unroll
    for (int f = 0; f < 4; ++f)
#pragma unroll
      for (int j = 0; j < 4; ++j)
        oacc[f][j] *= alpha[j];
#pragma unroll
    for (int f = 0; f < 4; ++f)
#pragma unroll
      for (int j = 0; j < 4; ++j)
        p_s[w][kq * 4 + j][16 * f + fr] = __float2bfloat16(sv[f][j]);
#pragma unroll
    for (int kk = 0; kk < 2; ++kk) {
      bf16x8 pf = *(const bf16x8*)&p_s[w][fr][kq * 8 + 32 * kk];
#pragma unroll
      for (int f = 0; f < 4; ++f) {
        int d = 16 * f + fr;
        int cc = kq * 8 + 32 * kk;
        uint32_t byte = ((uint32_t)d << 7) + 2u * (uint32_t)cc;
        byte ^= (uint32_t)(((d & 7) ^ (d >> 3)) << 4);
        bf16x8 vf = *(const bf16x8*)((char*)vt_s + byte);
        oacc[f] = __builtin_amdgcn_mfma_f32_16x16x32_bf16(pf, vf, oacc[f], 0, 0, 0);
      }
    }
  }

#pragma unroll
  for (int f = 0; f < 4; ++f)
#pragma unroll
    for (int j = 0; j < 4; ++j) {
      int r = 16 * w + kq * 4 + j;
      int d = 16 * f + fr;
      float o = oacc[f][j] / s_run[j];
      Y[(size_t)(b * LL + l0 + r) * DD + h * 64 + d] = __float2bfloat16(o);
    }
}

// ---------------- launch ----------------
extern "C" void kernel_launch(void* const* d_in, const int* in_sizes, int n_in,
                              void* d_out, int out_size, void* d_ws, size_t ws_size,
                              hipStream_t stream) {
  (void)in_sizes; (void)n_in; (void)out_size; (void)ws_size;
  const float* x     = (const float*)d_in[0];
  const float* ln1w  = (const float*)d_in[1];
  const float* ln1b  = (const float*)d_in[2];
  const float* Wqkv  = (const float*)d_in[3];
  const float* bqkv  = (const float*)d_in[4];
  const float* Wproj = (const float*)d_in[5];
  const float* bproj = (const float*)d_in[6];
  const float* Er    = (const float*)d_in[7];
  const float* ln2w  = (const float*)d_in[8];
  const float* ln2b  = (const float*)d_in[9];
  const float* Wfc   = (const float*)d_in[10];
  const float* bfc   = (const float*)d_in[11];
  const float* Wfc2  = (const float*)d_in[12];
  const float* bfc2  = (const float*)d_in[13];
  float* out = (float*)d_out;

  char* ws = (char*)d_ws;
  const size_t MB = 1ull << 20;
  __hip_bfloat16* h1    = (__hip_bfloat16*)(ws + 0);        // 8 MB
  __hip_bfloat16* qkvb  = (__hip_bfloat16*)(ws + 8 * MB);   // 24 MB
  __hip_bfloat16* mbuf  = (__hip_bfloat16*)(ws + 0);        // 32 MB (aliases h1+qkvb)
  __hip_bfloat16* yb    = (__hip_bfloat16*)(ws + 32 * MB);  // 8 MB
  __hip_bfloat16* h2    = (__hip_bfloat16*)(ws + 32 * MB);  // 8 MB (aliases yb)
  float*          x2    = (float*)(ws + 40 * MB);           // 16 MB
  __hip_bfloat16* Wqkvt = (__hip_bfloat16*)(ws + 56 * MB);  // 6 MB
  __hip_bfloat16* Erb   = (__hip_bfloat16*)(ws + 62 * MB);  // 128 KB
  __hip_bfloat16* Wprojt= (__hip_bfloat16*)(ws + 63 * MB);  // 2 MB
  __hip_bfloat16* Wfct  = (__hip_bfloat16*)(ws + 66 * MB);  // 8 MB
  __hip_bfloat16* Wfc2t = (__hip_bfloat16*)(ws + 75 * MB);  // 8 MB

  dim3 blk(256);

  transpose_cvt<<<dim3(3072 / 32, 1024 / 32), blk, 0, stream>>>(Wqkv, Wqkvt, 1024, 3072);
  transpose_cvt<<<dim3(1024 / 32, 1024 / 32), blk, 0, stream>>>(Wproj, Wprojt, 1024, 1024);
  transpose_cvt<<<dim3(4096 / 32, 1024 / 32), blk, 0, stream>>>(Wfc, Wfct, 1024, 4096);
  transpose_cvt<<<dim3(1024 / 32, 4096 / 32), blk, 0, stream>>>(Wfc2, Wfc2t, 4096, 1024);
  cvt_er<<<dim3(64), blk, 0, stream>>>(Er, Erb);

  ln_kernel<<<4096, blk, 0, stream>>>(x, ln1w, ln1b, h1);

  gemm256<0><<<dim3(3072 / 256, 4096 / 256), dim3(512), 0, stream>>>(
      h1, Wqkvt, bqkv, nullptr, qkvb, 4096, 3072, 1024);

  attn_mfma<<<dim3(1024), blk, 0, stream>>>(qkvb, Erb, yb);

  gemm128p<2><<<dim3(1024 / 128, 4096 / 128), blk, 0, stream>>>(
      yb, Wprojt, bproj, x, x2, 4096, 1024, 1024);

  ln_kernel<<<4096, blk, 0, stream>>>(x2, ln2w, ln2b, h2);

  gemm256<1><<<dim3(4096 / 256, 4096 / 256), dim3(512), 0, stream>>>(
      h2, Wfct, bfc, nullptr, mbuf, 4096, 4096, 1024);

  gemm128p<2><<<dim3(1024 / 128, 4096 / 128), blk, 0, stream>>>(
      mbuf, Wfc2t, bfc2, x2, out, 4096, 1024, 4096);
}